// Round 2
// baseline (2516.200 us; speedup 1.0000x reference)
//
#include <hip/hip_runtime.h>
#include <hip/hip_fp16.h>
#include <math.h>

#define NN 16384      // nodes
#define E1N 65536     // edges level 1
#define NBATCH 256
#define NC2 65536     // clusters (level 2 and level 3)
#define KH 128        // edge-MLP hidden
#define OC 16         // o-chunk for M
#define NCOLS (KH*OC) // 2048
#define NT 32         // node tile in mgemm

__device__ __forceinline__ float elu1(float x){ return x > 0.f ? x : expm1f(x); }

// hrelu[e,k] = relu(b1[k] + sum_i ea[e,i]*W1[i,k])  (fp16 out)
__global__ __launch_bounds__(256) void k_edge_mlp(const float* __restrict__ ea,
    const float* __restrict__ W1, const float* __restrict__ b1,
    __half* __restrict__ hrelu, int E){
  int t = blockIdx.x*256 + threadIdx.x;
  if (t >= E*KH) return;
  int e = t >> 7, k = t & 127;
  const float* row = ea + e*7;
  float acc = b1[k];
  #pragma unroll
  for (int i=0;i<7;i++) acc = fmaf(row[i], W1[i*KH+k], acc);
  hrelu[t] = __float2half(fmaxf(acc, 0.f));
}

// outb[n,o] = bias[o] + sum_i x[n,i]*root[i,o] ; bterm[n,o] = sum_i x[n,i]*b2[i,o]
__global__ __launch_bounds__(256) void k_prep(const float* __restrict__ x,
    const float* __restrict__ root, const float* __restrict__ bias,
    const float* __restrict__ b2, float* __restrict__ outb, float* __restrict__ bterm,
    int mi, int mo){
  int t = blockIdx.x*256 + threadIdx.x;
  if (t >= NN*mo) return;
  int n = t / mo, o = t - n*mo;
  const float* xr = x + n*mi;
  float a0 = bias[o], a1 = 0.f;
  for (int i=0;i<mi;i++){ float xv = xr[i]; a0 = fmaf(xv, root[i*mo+o], a0); a1 = fmaf(xv, b2[i*mo+o], a1); }
  outb[t] = a0; bterm[t] = a1;
}

// W2c[i, k*OC+oc] = W2[k, i*mo + ob+oc]
__global__ __launch_bounds__(256) void k_w2c(const float* __restrict__ W2,
    float* __restrict__ W2c, int mi, int mo, int ob){
  int t = blockIdx.x*256 + threadIdx.x;
  if (t >= mi*KH*OC) return;
  int oc = t % OC; int k = (t / OC) % KH; int i = t / (OC*KH);
  W2c[i*NCOLS + k*OC + oc] = W2[k*mi*mo + i*mo + ob + oc];
}

// Mc[n, j] = sum_i A[n,i]*Bc[i,j]   (A: [NN x MI], Bc: [MI x NCOLS]), fp16 out
template<int MI>
__global__ __launch_bounds__(256) void k_mgemm(const float* __restrict__ A,
    const float* __restrict__ Bc, __half* __restrict__ Mc){
  __shared__ float xs[NT][MI];
  int nb = blockIdx.x * NT;
  int j = blockIdx.y * 256 + threadIdx.x;
  for (int idx = threadIdx.x; idx < NT*MI; idx += 256)
    xs[idx / MI][idx % MI] = A[(size_t)(nb + idx/MI)*MI + (idx % MI)];
  __syncthreads();
  float acc[NT];
  #pragma unroll
  for (int n=0;n<NT;n++) acc[n]=0.f;
  #pragma unroll 4
  for (int i=0;i<MI;i++){
    float w = Bc[i*NCOLS + j];
    #pragma unroll
    for (int n=0;n<NT;n++) acc[n] = fmaf(xs[n][i], w, acc[n]);
  }
  #pragma unroll
  for (int n=0;n<NT;n++) Mc[(size_t)(nb+n)*NCOLS + j] = __float2half(acc[n]);
}

// per (e,oc): msg = bterm[src,ob+oc] + sum_k hrelu[e,k]*Mc[src,k*OC+oc]; atomicAdd out[dst,ob+oc]
__global__ __launch_bounds__(256) void k_msg(const int* __restrict__ src,
    const int* __restrict__ dst, const __half* __restrict__ hrelu,
    const __half* __restrict__ Mc, const float* __restrict__ bterm,
    float* __restrict__ outb, int mo, int ob){
  int t = blockIdx.x*256 + threadIdx.x;
  if (t >= E1N*OC) return;
  int e = t / OC, oc = t - e*OC;
  int s = src[e], d = dst[e];
  const __half* mrow = Mc + (size_t)s*NCOLS + oc;
  const __half* hr = hrelu + (size_t)e*KH;
  float acc = bterm[s*mo + ob + oc];
  #pragma unroll 8
  for (int k=0;k<KH;k++) acc = fmaf(__half2float(hr[k]), __half2float(mrow[k*OC]), acc);
  atomicAdd(&outb[d*mo + ob + oc], acc);
}

__global__ __launch_bounds__(256) void k_elu(float* __restrict__ v, int n){
  int t = blockIdx.x*256 + threadIdx.x;
  if (t < n) v[t] = elu1(v[t]);
}

// pool scatter: per (a,f): pool[cluster[a],f] += h[node[a],f]; cnt[cluster[a]] += 1 (f==0)
__global__ __launch_bounds__(256) void k_pool(const int* __restrict__ nodei,
    const int* __restrict__ clusteri, const float* __restrict__ h,
    float* __restrict__ pool, float* __restrict__ cnt, int A){
  int t = blockIdx.x*256 + threadIdx.x;
  if (t >= A*64) return;
  int a = t >> 6, f = t & 63;
  int c = clusteri[a], nd = nodei[a];
  atomicAdd(&pool[c*64+f], h[nd*64+f]);
  if (f==0) atomicAdd(&cnt[c], 1.f);
}

// GraphConv base with fused avg-pool-normalize + iso concat (din=128):
// xin[i] = i<64 ? pool[n,i]/max(cnt,1) : iso[n,i-64]
__global__ __launch_bounds__(256) void k_gc_base_pooled(const float* __restrict__ pool,
    const float* __restrict__ cnt, const float* __restrict__ iso,
    const float* __restrict__ Wrel, const float* __restrict__ Wroot,
    const float* __restrict__ bias, float* __restrict__ y, float* __restrict__ outb, int Nc){
  int t = blockIdx.x*256 + threadIdx.x;
  if (t >= Nc*64) return;
  int n = t >> 6, o = t & 63;
  float inv = 1.f / fmaxf(cnt[n], 1.f);
  const float* pr = pool + (size_t)n*64;
  const float* ir = iso + (size_t)n*64;
  float ar = 0.f, ao = bias[o];
  #pragma unroll 8
  for (int i=0;i<64;i++){ float xv = pr[i]*inv; ar = fmaf(xv, Wrel[i*64+o], ar); ao = fmaf(xv, Wroot[i*64+o], ao); }
  #pragma unroll 8
  for (int i=0;i<64;i++){ float xv = ir[i]; ar = fmaf(xv, Wrel[(64+i)*64+o], ar); ao = fmaf(xv, Wroot[(64+i)*64+o], ao); }
  y[t] = ar; outb[t] = ao;
}

// y[n,o] = sum_i x[n,i]*Wrel[i,o]; outb[n,o] = bias[o] + sum_i x[n,i]*Wroot[i,o]  (din=64)
__global__ __launch_bounds__(256) void k_gc_base64(const float* __restrict__ xin,
    const float* __restrict__ Wrel, const float* __restrict__ Wroot,
    const float* __restrict__ bias, float* __restrict__ y, float* __restrict__ outb, int Nc){
  int t = blockIdx.x*256 + threadIdx.x;
  if (t >= Nc*64) return;
  int n = t >> 6, o = t & 63;
  const float* xr = xin + (size_t)n*64;
  float ar = 0.f, ao = bias[o];
  #pragma unroll 8
  for (int i=0;i<64;i++){ float xv = xr[i]; ar = fmaf(xv, Wrel[i*64+o], ar); ao = fmaf(xv, Wroot[i*64+o], ao); }
  y[t] = ar; outb[t] = ao;
}

__global__ __launch_bounds__(256) void k_gc_scatter(const int* __restrict__ src,
    const int* __restrict__ dst, const float* __restrict__ y,
    float* __restrict__ outb, int E){
  int t = blockIdx.x*256 + threadIdx.x;
  if (t >= E*64) return;
  int e = t >> 6, o = t & 63;
  atomicAdd(&outb[(size_t)dst[e]*64 + o], y[(size_t)src[e]*64 + o]);
}

__global__ __launch_bounds__(256) void k_batchsum(const int* __restrict__ b,
    const float* __restrict__ h, float* __restrict__ x123, int Nc, int off){
  int t = blockIdx.x*256 + threadIdx.x;
  if (t >= Nc*64) return;
  int n = t >> 6, f = t & 63;
  atomicAdd(&x123[b[n]*192 + off + f], h[t]);
}

// fc1 with the concat([xc,xc]) folding: Weff = W[0:192] + W[192:384]
__global__ __launch_bounds__(256) void k_fc1(const float* __restrict__ x123,
    const float* __restrict__ W, const float* __restrict__ b, float* __restrict__ t1){
  int t = blockIdx.x*256 + threadIdx.x;
  if (t >= NBATCH*64) return;
  int bb = t >> 6, o = t & 63;
  const float* xr = x123 + bb*192;
  float acc = b[o];
  for (int j=0;j<192;j++) acc = fmaf(xr[j], W[j*64+o] + W[(192+j)*64+o], acc);
  t1[t] = elu1(acc);
}

__global__ __launch_bounds__(256) void k_fc2(const float* __restrict__ t1,
    const float* __restrict__ W, const float* __restrict__ b, float* __restrict__ t2){
  int t = blockIdx.x*256 + threadIdx.x;
  if (t >= NBATCH*32) return;
  int bb = t >> 5, o = t & 31;
  float acc = b[o];
  for (int j=0;j<64;j++) acc = fmaf(t1[bb*64+j], W[j*32+o], acc);
  t2[t] = elu1(acc);
}

__global__ __launch_bounds__(256) void k_fc3(const float* __restrict__ t2,
    const float* __restrict__ W, const float* __restrict__ b, float* __restrict__ out){
  int t = blockIdx.x*256 + threadIdx.x;
  if (t >= NBATCH) return;
  float acc = b[0];
  for (int j=0;j<32;j++) acc = fmaf(t2[t*32+j], W[j], acc);
  out[t] = acc;
}

static inline int cdiv(long long a, int b){ return (int)((a + b - 1) / b); }

extern "C" void kernel_launch(void* const* d_in, const int* in_sizes, int n_in,
                              void* d_out, int out_size, void* d_ws, size_t ws_size,
                              hipStream_t stream) {
  const float* x0    = (const float*)d_in[0];
  const int*   ei    = (const int*)d_in[1];
  const float* ea    = (const float*)d_in[2];
  const int*   batch = (const int*)d_in[3];
  const int*   a2n   = (const int*)d_in[4];
  const int*   a2c   = (const int*)d_in[5];
  const float* iso2  = (const float*)d_in[6];
  const int*   ei2   = (const int*)d_in[7];
  const int*   b2arr = (const int*)d_in[8];
  const int*   a3n   = (const int*)d_in[9];
  const int*   a3c   = (const int*)d_in[10];
  const float* iso3  = (const float*)d_in[11];
  const int*   ei3   = (const int*)d_in[12];
  const int*   b3arr = (const int*)d_in[13];
  const float* nnp[3][6];
  for (int c=0;c<3;c++) for (int p=0;p<6;p++) nnp[c][p] = (const float*)d_in[14 + 6*c + p];
  const float* c4W[3]; const float* c5W[3]; const float* c6W[3]; const float* c7W[3];
  for (int p=0;p<3;p++){ c4W[p]=(const float*)d_in[32+p]; c5W[p]=(const float*)d_in[35+p];
                         c6W[p]=(const float*)d_in[38+p]; c7W[p]=(const float*)d_in[41+p]; }
  const float* fc1W=(const float*)d_in[44]; const float* fc1b=(const float*)d_in[45];
  const float* fc2W=(const float*)d_in[46]; const float* fc2b=(const float*)d_in[47];
  const float* fc3W=(const float*)d_in[48]; const float* fc3b=(const float*)d_in[49];
  float* outp = (float*)d_out;

  // ---- workspace carve (total ~102 MB; phase-2 buffers alias phase-1 scratch) ----
  const size_t SZ_HRELU = (size_t)E1N*KH*2;      // 16 MB  fp16
  const size_t SZ_MC    = (size_t)NN*NCOLS*2;    // 64 MB  fp16
  const size_t SZ_W2C   = (size_t)64*NCOLS*4;    // 0.5 MB
  const size_t SZ_BTERM = (size_t)NN*64*4;       // 4 MB
  const size_t SZ_R0    = SZ_HRELU + SZ_MC + SZ_W2C + SZ_BTERM;  // 84.5 MB
  char* ws = (char*)d_ws; size_t off = 0;
  auto alloc = [&](size_t bytes)->void*{ void* p = ws + off; off += (bytes + 255) & ~(size_t)255; return p; };
  char* r0 = (char*)alloc(SZ_R0);
  // phase-1 view of r0
  __half* hrelu = (__half*)r0;
  __half* Mc    = (__half*)(r0 + SZ_HRELU);
  float*  W2c   = (float*)(r0 + SZ_HRELU + SZ_MC);
  float*  bterm = (float*)(r0 + SZ_HRELU + SZ_MC + SZ_W2C);
  // phase-2 view of r0 (64.25 MB <= 84.5 MB; phase-1 data dead by then)
  float* pool = (float*)r0;                                  // 16 MB
  float* cnt  = (float*)(r0 + (size_t)NC2*64*4);             // 0.25 MB
  float* ybuf = (float*)(r0 + (size_t)NC2*65*4);             // 16 MB
  float* gA   = (float*)(r0 + (size_t)NC2*(65+64)*4);        // 16 MB
  float* gB   = (float*)(r0 + (size_t)NC2*(65+128)*4);       // 16 MB
  // persistent
  float* hA   = (float*)alloc((size_t)NN*64*4);
  float* hB   = (float*)alloc((size_t)NN*64*4);
  float* hC   = (float*)alloc((size_t)NN*64*4);
  float* x123 = (float*)alloc((size_t)NBATCH*192*4);
  float* t1   = (float*)alloc((size_t)NBATCH*64*4);
  float* t2   = (float*)alloc((size_t)NBATCH*32*4);
  (void)ws_size; (void)n_in; (void)in_sizes; (void)out_size;

  const int* src1 = ei; const int* dst1 = ei + E1N;

  // ---- NNConv x3 ----
  auto run_nnconv = [&](const float* xin, int mi, int mo, const float* const* P, float* outb){
    const float* W1=P[0]; const float* b1=P[1]; const float* W2=P[2];
    const float* b2=P[3]; const float* root=P[4]; const float* bias=P[5];
    k_edge_mlp<<<cdiv((long long)E1N*KH,256),256,0,stream>>>(ea, W1, b1, hrelu, E1N);
    k_prep<<<cdiv((long long)NN*mo,256),256,0,stream>>>(xin, root, bias, b2, outb, bterm, mi, mo);
    for (int ob = 0; ob < mo; ob += OC){
      k_w2c<<<cdiv((long long)mi*KH*OC,256),256,0,stream>>>(W2, W2c, mi, mo, ob);
      dim3 g(NN/NT, NCOLS/256);
      if (mi==16)      k_mgemm<16><<<g,256,0,stream>>>(xin, W2c, Mc);
      else if (mi==32) k_mgemm<32><<<g,256,0,stream>>>(xin, W2c, Mc);
      else             k_mgemm<64><<<g,256,0,stream>>>(xin, W2c, Mc);
      k_msg<<<cdiv((long long)E1N*OC,256),256,0,stream>>>(src1, dst1, hrelu, Mc, bterm, outb, mo, ob);
    }
    k_elu<<<cdiv((long long)NN*mo,256),256,0,stream>>>(outb, NN*mo);
  };
  run_nnconv(x0, 16, 32, nnp[0], hA);
  run_nnconv(hA, 32, 64, nnp[1], hB);
  run_nnconv(hB, 64, 64, nnp[2], hC);

  hipMemsetAsync(x123, 0, (size_t)NBATCH*192*4, stream);
  k_batchsum<<<cdiv((long long)NN*64,256),256,0,stream>>>(batch, hC, x123, NN, 0);

  // ---- levels 2 and 3 ----
  auto run_level = [&](const int* an, const int* ac, int A, const float* iso,
                       const int* eiL, int EL, const int* batchL,
                       const float* const* cA, const float* const* cB, int off123){
    hipMemsetAsync(pool, 0, (size_t)NC2*64*4, stream);
    hipMemsetAsync(cnt, 0, (size_t)NC2*4, stream);
    k_pool<<<cdiv((long long)A*64,256),256,0,stream>>>(an, ac, hC, pool, cnt, A);
    k_gc_base_pooled<<<cdiv((long long)NC2*64,256),256,0,stream>>>(pool, cnt, iso, cA[0], cA[1], cA[2], ybuf, gA, NC2);
    k_gc_scatter<<<cdiv((long long)EL*64,256),256,0,stream>>>(eiL, eiL+EL, ybuf, gA, EL);
    k_elu<<<cdiv((long long)NC2*64,256),256,0,stream>>>(gA, NC2*64);
    k_gc_base64<<<cdiv((long long)NC2*64,256),256,0,stream>>>(gA, cB[0], cB[1], cB[2], ybuf, gB, NC2);
    k_gc_scatter<<<cdiv((long long)EL*64,256),256,0,stream>>>(eiL, eiL+EL, ybuf, gB, EL);
    k_elu<<<cdiv((long long)NC2*64,256),256,0,stream>>>(gB, NC2*64);
    k_batchsum<<<cdiv((long long)NC2*64,256),256,0,stream>>>(batchL, gB, x123, NC2, off123);
  };
  run_level(a2n, a2c, 131072, iso2, ei2, 262144, b2arr, c4W, c5W, 64);
  run_level(a3n, a3c, 196608, iso3, ei3, 262144, b3arr, c6W, c7W, 128);

  // ---- FC head ----
  k_fc1<<<cdiv((long long)NBATCH*64,256),256,0,stream>>>(x123, fc1W, fc1b, t1);
  k_fc2<<<cdiv((long long)NBATCH*32,256),256,0,stream>>>(t1, fc2W, fc2b, t2);
  k_fc3<<<cdiv(NBATCH,256),256,0,stream>>>(t2, fc3W, fc3b, outp);
}

// Round 3
// 2078.980 us; speedup vs baseline: 1.2103x; 1.2103x over previous
//
#include <hip/hip_runtime.h>
#include <math.h>

#define NN 16384      // nodes
#define E1N 65536     // edges level 1
#define NBATCH 256
#define NC2 65536     // clusters (level 2 and level 3)
#define KH 128        // edge-MLP hidden
#define OC 16         // o-chunk for M
#define NCOLS (KH*OC) // 2048

typedef _Float16 f16;
typedef _Float16 f16x8 __attribute__((ext_vector_type(8)));
typedef float    f32x4 __attribute__((ext_vector_type(4)));

__device__ __forceinline__ float elu1(float x){ return x > 0.f ? x : expm1f(x); }

// ---------------- CSR build (edges sorted by src) ----------------
__global__ __launch_bounds__(256) void k_deg(const int* __restrict__ ei, int* __restrict__ deg){
  int e = blockIdx.x*256 + threadIdx.x;
  if (e < E1N) atomicAdd(&deg[ei[e]], 1);
}

__global__ __launch_bounds__(256) void k_scan(const int* __restrict__ deg, int* __restrict__ cursor){
  __shared__ int buf[256];
  __shared__ int carry;
  if (threadIdx.x == 0) carry = 0;
  __syncthreads();
  for (int base = 0; base < NN; base += 256){
    int v = deg[base + threadIdx.x];
    buf[threadIdx.x] = v; __syncthreads();
    for (int o = 1; o < 256; o <<= 1){
      int t = (threadIdx.x >= o) ? buf[threadIdx.x - o] : 0;
      __syncthreads();
      buf[threadIdx.x] += t;
      __syncthreads();
    }
    int incl = buf[threadIdx.x];
    cursor[base + threadIdx.x] = carry + incl - v;
    __syncthreads();
    if (threadIdx.x == 255) carry += incl;
    __syncthreads();
  }
}

__global__ __launch_bounds__(256) void k_fill(const int* __restrict__ ei, int* __restrict__ cursor,
    int* __restrict__ eids, int* __restrict__ srcs, int* __restrict__ dsts){
  int e = blockIdx.x*256 + threadIdx.x;
  if (e >= E1N) return;
  int s = ei[e];
  int p = atomicAdd(&cursor[s], 1);
  eids[p] = e; srcs[p] = s; dsts[p] = ei[E1N + e];
}

// ---------------- small converts ----------------
__global__ __launch_bounds__(256) void k_cvt16(const float* __restrict__ v, f16* __restrict__ o, int n){
  int t = blockIdx.x*256 + threadIdx.x;
  if (t < n) o[t] = (f16)v[t];
}

__global__ __launch_bounds__(256) void k_elu_both(float* __restrict__ v, f16* __restrict__ v16, int n){
  int t = blockIdx.x*256 + threadIdx.x;
  if (t < n){ float r = elu1(v[t]); v[t] = r; v16[t] = (f16)r; }
}

__global__ __launch_bounds__(256) void k_elu(float* __restrict__ v, int n){
  int t = blockIdx.x*256 + threadIdx.x;
  if (t < n) v[t] = elu1(v[t]);
}

// ---------------- NNConv pieces ----------------
// hrelu[p,k] (sorted edge order) = relu(b1[k] + sum_i ea[eids[p],i]*W1[i,k])
__global__ __launch_bounds__(256) void k_edge_mlp(const float* __restrict__ ea,
    const int* __restrict__ eids,
    const float* __restrict__ W1, const float* __restrict__ b1,
    f16* __restrict__ hrelu){
  int t = blockIdx.x*256 + threadIdx.x;
  if (t >= E1N*KH) return;
  int p = t >> 7, k = t & 127;
  const float* row = ea + (size_t)eids[p]*7;
  float acc = b1[k];
  #pragma unroll
  for (int i=0;i<7;i++) acc = fmaf(row[i], W1[i*KH+k], acc);
  hrelu[t] = (f16)fmaxf(acc, 0.f);
}

// outb[n,o] = bias[o] + sum_i x[n,i]*root[i,o] ; bterm[n,o] = sum_i x[n,i]*b2[i,o]
__global__ __launch_bounds__(256) void k_prep(const float* __restrict__ x,
    const float* __restrict__ root, const float* __restrict__ bias,
    const float* __restrict__ b2, float* __restrict__ outb, float* __restrict__ bterm,
    int mi, int mo){
  int t = blockIdx.x*256 + threadIdx.x;
  if (t >= NN*mo) return;
  int n = t / mo, o = t - n*mo;
  const float* xr = x + (size_t)n*mi;
  float a0 = bias[o], a1 = 0.f;
  for (int i=0;i<mi;i++){ float xv = xr[i]; a0 = fmaf(xv, root[i*mo+o], a0); a1 = fmaf(xv, b2[i*mo+o], a1); }
  outb[t] = a0; bterm[t] = a1;
}

// pack W2 chunk into MFMA B-fragment order (fp16):
// Bp[((c*S+s)*64 + l)*8 + j] = W2[k_out=c][i = s*32+(l>>4)*8+j][ob + (l&15)]  (0 if i>=mi)
__global__ __launch_bounds__(256) void k_w2pack(const float* __restrict__ W2,
    f16* __restrict__ Bp, int mi, int mo, int ob, int S){
  int t = blockIdx.x*256 + threadIdx.x;
  if (t >= 128*S*512) return;
  int j = t & 7, l = (t >> 3) & 63, cs = t >> 9;
  int s = cs % S, c = cs / S;
  int i = s*32 + ((l>>4)<<3) + j;
  int oc = l & 15;
  float v = (i < mi) ? W2[(size_t)c*mi*mo + (size_t)i*mo + ob + oc] : 0.f;
  Bp[t] = (f16)v;
}

// Mc[16384 x 2048] = A[16384 x MI] @ B[MI x 2048]  via MFMA, fp16 out, LDS-repacked stores
template<int MI, int S>
__global__ __launch_bounds__(256) void k_mgemm_mfma(const f16* __restrict__ A,
    const f16* __restrict__ Bp, f16* __restrict__ Mc){
  __shared__ __align__(16) f16 tile[64*128];   // 16 KB
  int l = threadIdx.x & 63, w = threadIdx.x >> 6;
  int r0 = blockIdx.x*64 + w*16;
  int cb = blockIdx.y*8;
  const f16* arow = A + (size_t)(r0 + (l & 15))*MI;
  f16x8 a[S];
  #pragma unroll
  for (int s=0;s<S;s++){
    int koff = s*32 + ((l>>4)<<3);
    if (koff < MI) a[s] = *(const f16x8*)(arow + koff);
    else           a[s] = (f16x8){0,0,0,0,0,0,0,0};
  }
  f32x4 acc[8];
  #pragma unroll
  for (int c=0;c<8;c++) acc[c] = (f32x4){0.f,0.f,0.f,0.f};
  #pragma unroll
  for (int c=0;c<8;c++){
    #pragma unroll
    for (int s=0;s<S;s++){
      f16x8 b = *(const f16x8*)(Bp + ((size_t)((cb + c)*S + s)*64 + l)*8);
      acc[c] = __builtin_amdgcn_mfma_f32_16x16x32_f16(a[s], b, acc[c], 0, 0, 0);
    }
  }
  // write frags to LDS: tile[local_row][local_col], local rows of this wave at w*16
  f16* tw = tile + w*16*128;
  #pragma unroll
  for (int c=0;c<8;c++)
    #pragma unroll
    for (int r=0;r<4;r++)
      tw[(((l>>4)<<2) + r)*128 + c*16 + (l&15)] = (f16)acc[c][r];
  __syncthreads();
  // coalesced stores: 64 rows x 256 B
  int rr = threadIdx.x >> 2, q = threadIdx.x & 3;
  const uint4* sl = (const uint4*)tile;
  uint4* dst = (uint4*)Mc;
  size_t rowbase = (size_t)(blockIdx.x*64 + rr)*256 + blockIdx.y*16;
  #pragma unroll
  for (int i=0;i<4;i++)
    dst[rowbase + q*4 + i] = sl[rr*16 + q*4 + i];
}

// per sorted-edge thread: msg[oc] = bterm[s,ob+oc] + sum_k hrelu[p,k]*Mc[s,k*16+oc]; atomic to outb[d]
__global__ __launch_bounds__(256) void k_msg(const int* __restrict__ srcs,
    const int* __restrict__ dsts, const f16* __restrict__ hrelu,
    const f16* __restrict__ Mc, const float* __restrict__ bterm,
    float* __restrict__ outb, int mo, int ob){
  int e = blockIdx.x*256 + threadIdx.x;
  if (e >= E1N) return;
  int s = srcs[e], d = dsts[e];
  float acc[16];
  {
    const float4* bt = (const float4*)(bterm + (size_t)s*mo + ob);
    float4 bb[4];
    #pragma unroll
    for (int q=0;q<4;q++) bb[q] = bt[q];
    const float* bf = (const float*)bb;
    #pragma unroll
    for (int oc=0;oc<16;oc++) acc[oc] = bf[oc];
  }
  const f16x8* hr = (const f16x8*)(hrelu + (size_t)e*KH);
  const f16x8* mr = (const f16x8*)(Mc + (size_t)s*NCOLS);
  #pragma unroll 2
  for (int kk=0;kk<16;kk++){
    f16x8 h8 = hr[kk];
    #pragma unroll
    for (int j=0;j<8;j++){
      float hf = (float)h8[j];
      int k = kk*8 + j;
      f16x8 m0 = mr[k*2], m1 = mr[k*2+1];
      #pragma unroll
      for (int oc=0;oc<8;oc++){
        acc[oc]   = fmaf(hf, (float)m0[oc], acc[oc]);
        acc[8+oc] = fmaf(hf, (float)m1[oc], acc[8+oc]);
      }
    }
  }
  float* ob_ptr = outb + (size_t)d*mo + ob;
  #pragma unroll
  for (int oc=0;oc<16;oc++) atomicAdd(&ob_ptr[oc], acc[oc]);
}

// ---------------- pooling / GraphConv ----------------
__global__ __launch_bounds__(256) void k_pool(const int* __restrict__ nodei,
    const int* __restrict__ clusteri, const float* __restrict__ h,
    float* __restrict__ pool, float* __restrict__ cnt, int A){
  int t = blockIdx.x*256 + threadIdx.x;
  if (t >= A*64) return;
  int a = t >> 6, f = t & 63;
  int c = clusteri[a], nd = nodei[a];
  atomicAdd(&pool[c*64+f], h[nd*64+f]);
  if (f==0) atomicAdd(&cnt[c], 1.f);
}

// h16[c,0:64] = pool/max(cnt,1) ; h16[c,64:128] = iso   (fp16)
__global__ __launch_bounds__(256) void k_buildh16(const float* __restrict__ pool,
    const float* __restrict__ cnt, const float* __restrict__ iso,
    f16* __restrict__ h16){
  int t = blockIdx.x*256 + threadIdx.x;
  if (t >= NC2*128) return;
  int c = t >> 7, f = t & 127;
  float v = (f < 64) ? pool[c*64+f] / fmaxf(cnt[c], 1.f) : iso[(size_t)c*64 + (f-64)];
  h16[t] = (f16)v;
}

// pack [Wrel | Wroot] (each K x 64 fp32) into B-frag order, N=128
__global__ __launch_bounds__(256) void k_packB_gc(const float* __restrict__ Wrel,
    const float* __restrict__ Wroot, f16* __restrict__ Bp, int S){
  int t = blockIdx.x*256 + threadIdx.x;
  if (t >= 8*S*512) return;
  int j = t & 7, l = (t >> 3) & 63, cs = t >> 9;
  int s = cs % S, c = cs / S;
  int k = s*32 + ((l>>4)<<3) + j;
  int n = (c<<4) + (l & 15);
  float v = (n < 64) ? Wrel[k*64 + n] : Wroot[k*64 + (n - 64)];
  Bp[t] = (f16)v;
}

// [65536 x K] @ [K x 128] -> y (cols 0:64, fp32), outb (cols 64:128, +bias, fp32)
template<int S>
__global__ __launch_bounds__(256) void k_gc_mfma(const f16* __restrict__ A,
    const f16* __restrict__ Bp, const float* __restrict__ bias,
    float* __restrict__ y, float* __restrict__ outb){
  int l = threadIdx.x & 63, w = threadIdx.x >> 6;
  int r0 = blockIdx.x*64 + w*16;
  const f16* arow = A + (size_t)(r0 + (l & 15))*(S*32);
  f16x8 a[S];
  #pragma unroll
  for (int s=0;s<S;s++) a[s] = *(const f16x8*)(arow + s*32 + ((l>>4)<<3));
  f32x4 acc[8];
  #pragma unroll
  for (int c=0;c<8;c++) acc[c] = (f32x4){0.f,0.f,0.f,0.f};
  #pragma unroll
  for (int c=0;c<8;c++){
    #pragma unroll
    for (int s=0;s<S;s++){
      f16x8 b = *(const f16x8*)(Bp + ((size_t)(c*S + s)*64 + l)*8);
      acc[c] = __builtin_amdgcn_mfma_f32_16x16x32_f16(a[s], b, acc[c], 0, 0, 0);
    }
  }
  #pragma unroll
  for (int c=0;c<8;c++){
    int col = c*16 + (l & 15);
    #pragma unroll
    for (int r=0;r<4;r++){
      int row = r0 + ((l>>4)<<2) + r;
      if (col < 64) y[(size_t)row*64 + col] = acc[c][r];
      else          outb[(size_t)row*64 + (col-64)] = acc[c][r] + bias[col-64];
    }
  }
}

__global__ __launch_bounds__(256) void k_gc_scatter(const int* __restrict__ src,
    const int* __restrict__ dst, const float* __restrict__ y,
    float* __restrict__ outb, int E){
  int t = blockIdx.x*256 + threadIdx.x;
  if (t >= E*64) return;
  int e = t >> 6, o = t & 63;
  atomicAdd(&outb[(size_t)dst[e]*64 + o], y[(size_t)src[e]*64 + o]);
}

__global__ __launch_bounds__(256) void k_batchsum(const int* __restrict__ b,
    const float* __restrict__ h, float* __restrict__ x123, int Nc, int off){
  int t = blockIdx.x*256 + threadIdx.x;
  if (t >= Nc*64) return;
  int n = t >> 6, f = t & 63;
  atomicAdd(&x123[b[n]*192 + off + f], h[t]);
}

// ---------------- FC head ----------------
__global__ __launch_bounds__(256) void k_fc1(const float* __restrict__ x123,
    const float* __restrict__ W, const float* __restrict__ b, float* __restrict__ t1){
  int t = blockIdx.x*256 + threadIdx.x;
  if (t >= NBATCH*64) return;
  int bb = t >> 6, o = t & 63;
  const float* xr = x123 + bb*192;
  float acc = b[o];
  for (int j=0;j<192;j++) acc = fmaf(xr[j], W[j*64+o] + W[(192+j)*64+o], acc);
  t1[t] = elu1(acc);
}

__global__ __launch_bounds__(256) void k_fc2(const float* __restrict__ t1,
    const float* __restrict__ W, const float* __restrict__ b, float* __restrict__ t2){
  int t = blockIdx.x*256 + threadIdx.x;
  if (t >= NBATCH*32) return;
  int bb = t >> 5, o = t & 31;
  float acc = b[o];
  for (int j=0;j<64;j++) acc = fmaf(t1[bb*64+j], W[j*32+o], acc);
  t2[t] = elu1(acc);
}

__global__ __launch_bounds__(256) void k_fc3(const float* __restrict__ t2,
    const float* __restrict__ W, const float* __restrict__ b, float* __restrict__ out){
  int t = blockIdx.x*256 + threadIdx.x;
  if (t >= NBATCH) return;
  float acc = b[0];
  for (int j=0;j<32;j++) acc = fmaf(t2[t*32+j], W[j], acc);
  out[t] = acc;
}

static inline int cdiv(long long a, int b){ return (int)((a + b - 1) / b); }

extern "C" void kernel_launch(void* const* d_in, const int* in_sizes, int n_in,
                              void* d_out, int out_size, void* d_ws, size_t ws_size,
                              hipStream_t stream) {
  const float* x0    = (const float*)d_in[0];
  const int*   ei    = (const int*)d_in[1];
  const float* ea    = (const float*)d_in[2];
  const int*   batch = (const int*)d_in[3];
  const int*   a2n   = (const int*)d_in[4];
  const int*   a2c   = (const int*)d_in[5];
  const float* iso2  = (const float*)d_in[6];
  const int*   ei2   = (const int*)d_in[7];
  const int*   b2arr = (const int*)d_in[8];
  const int*   a3n   = (const int*)d_in[9];
  const int*   a3c   = (const int*)d_in[10];
  const float* iso3  = (const float*)d_in[11];
  const int*   ei3   = (const int*)d_in[12];
  const int*   b3arr = (const int*)d_in[13];
  const float* nnp[3][6];
  for (int c=0;c<3;c++) for (int p=0;p<6;p++) nnp[c][p] = (const float*)d_in[14 + 6*c + p];
  const float* c4W[3]; const float* c5W[3]; const float* c6W[3]; const float* c7W[3];
  for (int p=0;p<3;p++){ c4W[p]=(const float*)d_in[32+p]; c5W[p]=(const float*)d_in[35+p];
                         c6W[p]=(const float*)d_in[38+p]; c7W[p]=(const float*)d_in[41+p]; }
  const float* fc1W=(const float*)d_in[44]; const float* fc1b=(const float*)d_in[45];
  const float* fc2W=(const float*)d_in[46]; const float* fc2b=(const float*)d_in[47];
  const float* fc3W=(const float*)d_in[48]; const float* fc3b=(const float*)d_in[49];
  float* outp = (float*)d_out;

  // ---- workspace carve ----
  char* ws = (char*)d_ws; size_t off = 0;
  auto alloc = [&](size_t bytes)->void*{ void* p = ws + off; off += (bytes + 255) & ~(size_t)255; return p; };
  const size_t SZ_R0 = (size_t)92*1024*1024;
  char* r0 = (char*)alloc(SZ_R0);
  // phase-1 view (NNConv):  hrelu 16MB | Mc 64MB | W2p 256KB | bterm 4MB
  f16*   hrelu = (f16*)r0;
  f16*   Mc    = (f16*)(r0 + (size_t)E1N*KH*2);
  f16*   W2p   = (f16*)(r0 + (size_t)E1N*KH*2 + (size_t)NN*NCOLS*2);
  float* bterm = (float*)(r0 + (size_t)E1N*KH*2 + (size_t)NN*NCOLS*2 + 256*1024);
  // phase-2 view (levels): pool 16MB | cnt .25MB | ybuf 16MB | gA 16MB | gB 16MB | h16 16MB | g16 8MB | BpGc 32KB
  float* pool = (float*)r0;
  float* cnt  = (float*)(r0 + (size_t)NC2*64*4);
  float* ybuf = (float*)(r0 + (size_t)NC2*65*4);
  float* gA   = (float*)(r0 + (size_t)NC2*(65+64)*4);
  float* gB   = (float*)(r0 + (size_t)NC2*(65+128)*4);
  f16*   h16  = (f16*)  (r0 + (size_t)NC2*(65+192)*4);
  f16*   g16  = (f16*)  (r0 + (size_t)NC2*(65+192)*4 + (size_t)NC2*128*2);
  f16*   BpGc = (f16*)  (r0 + (size_t)NC2*(65+192)*4 + (size_t)NC2*192*2);
  // persistent
  float* hA    = (float*)alloc((size_t)NN*32*4);
  float* hB    = (float*)alloc((size_t)NN*64*4);
  float* hC    = (float*)alloc((size_t)NN*64*4);
  f16*   x016  = (f16*)  alloc((size_t)NN*16*2);
  f16*   hA16  = (f16*)  alloc((size_t)NN*32*2);
  f16*   hB16  = (f16*)  alloc((size_t)NN*64*2);
  int*   deg   = (int*)  alloc((size_t)NN*4);
  int*   cursor= (int*)  alloc((size_t)NN*4);
  int*   eids  = (int*)  alloc((size_t)E1N*4);
  int*   srcs  = (int*)  alloc((size_t)E1N*4);
  int*   dsts  = (int*)  alloc((size_t)E1N*4);
  float* x123  = (float*)alloc((size_t)NBATCH*192*4);
  float* t1    = (float*)alloc((size_t)NBATCH*64*4);
  float* t2    = (float*)alloc((size_t)NBATCH*32*4);
  (void)ws_size; (void)n_in; (void)in_sizes; (void)out_size;

  // ---- CSR: sort edges by src (once; reused by all 3 convs) ----
  hipMemsetAsync(deg, 0, (size_t)NN*4, stream);
  k_deg<<<cdiv(E1N,256),256,0,stream>>>(ei, deg);
  k_scan<<<1,256,0,stream>>>(deg, cursor);
  k_fill<<<cdiv(E1N,256),256,0,stream>>>(ei, cursor, eids, srcs, dsts);
  k_cvt16<<<cdiv((long long)NN*16,256),256,0,stream>>>(x0, x016, NN*16);

  // ---- NNConv x3 ----
  auto run_nnconv = [&](const float* xin, const f16* xin16, int mi, int mo,
                        const float* const* P, float* outb, f16* out16){
    const float* W1=P[0]; const float* b1=P[1]; const float* W2=P[2];
    const float* b2=P[3]; const float* root=P[4]; const float* bias=P[5];
    k_edge_mlp<<<cdiv((long long)E1N*KH,256),256,0,stream>>>(ea, eids, W1, b1, hrelu);
    k_prep<<<cdiv((long long)NN*mo,256),256,0,stream>>>(xin, root, bias, b2, outb, bterm, mi, mo);
    const int S = (mi > 32) ? 2 : 1;
    for (int ob = 0; ob < mo; ob += OC){
      k_w2pack<<<cdiv((long long)128*S*512,256),256,0,stream>>>(W2, W2p, mi, mo, ob, S);
      dim3 g(NN/64, NCOLS/128);
      if (mi==16)      k_mgemm_mfma<16,1><<<g,256,0,stream>>>(xin16, W2p, Mc);
      else if (mi==32) k_mgemm_mfma<32,1><<<g,256,0,stream>>>(xin16, W2p, Mc);
      else             k_mgemm_mfma<64,2><<<g,256,0,stream>>>(xin16, W2p, Mc);
      k_msg<<<cdiv(E1N,256),256,0,stream>>>(srcs, dsts, hrelu, Mc, bterm, outb, mo, ob);
    }
    k_elu_both<<<cdiv((long long)NN*mo,256),256,0,stream>>>(outb, out16, NN*mo);
  };
  run_nnconv(x0, x016, 16, 32, nnp[0], hA, hA16);
  run_nnconv(hA, hA16, 32, 64, nnp[1], hB, hB16);
  run_nnconv(hB, hB16, 64, 64, nnp[2], hC, hB16 /*unused after*/);

  hipMemsetAsync(x123, 0, (size_t)NBATCH*192*4, stream);
  k_batchsum<<<cdiv((long long)NN*64,256),256,0,stream>>>(batch, hC, x123, NN, 0);

  // ---- levels 2 and 3 ----
  auto run_level = [&](const int* an, const int* ac, int A, const float* iso,
                       const int* eiL, int EL, const int* batchL,
                       const float* const* cA, const float* const* cB, int off123){
    hipMemsetAsync(pool, 0, (size_t)NC2*64*4, stream);
    hipMemsetAsync(cnt, 0, (size_t)NC2*4, stream);
    k_pool<<<cdiv((long long)A*64,256),256,0,stream>>>(an, ac, hC, pool, cnt, A);
    k_buildh16<<<cdiv((long long)NC2*128,256),256,0,stream>>>(pool, cnt, iso, h16);
    k_packB_gc<<<cdiv((long long)8*4*512,256),256,0,stream>>>(cA[0], cA[1], BpGc, 4);
    k_gc_mfma<4><<<NC2/64,256,0,stream>>>(h16, BpGc, cA[2], ybuf, gA);
    k_gc_scatter<<<cdiv((long long)EL*64,256),256,0,stream>>>(eiL, eiL+EL, ybuf, gA, EL);
    k_elu_both<<<cdiv((long long)NC2*64,256),256,0,stream>>>(gA, g16, NC2*64);
    k_packB_gc<<<cdiv((long long)8*2*512,256),256,0,stream>>>(cB[0], cB[1], BpGc, 2);
    k_gc_mfma<2><<<NC2/64,256,0,stream>>>(g16, BpGc, cB[2], ybuf, gB);
    k_gc_scatter<<<cdiv((long long)EL*64,256),256,0,stream>>>(eiL, eiL+EL, ybuf, gB, EL);
    k_elu<<<cdiv((long long)NC2*64,256),256,0,stream>>>(gB, NC2*64);
    k_batchsum<<<cdiv((long long)NC2*64,256),256,0,stream>>>(batchL, gB, x123, NC2, off123);
  };
  run_level(a2n, a2c, 131072, iso2, ei2, 262144, b2arr, c4W, c5W, 64);
  run_level(a3n, a3c, 196608, iso3, ei3, 262144, b3arr, c6W, c7W, 128);

  // ---- FC head ----
  k_fc1<<<cdiv((long long)NBATCH*64,256),256,0,stream>>>(x123, fc1W, fc1b, t1);
  k_fc2<<<cdiv((long long)NBATCH*32,256),256,0,stream>>>(t1, fc2W, fc2b, t2);
  k_fc3<<<cdiv(NBATCH,256),256,0,stream>>>(t2, fc3W, fc3b, outp);
}

// Round 4
// 1486.759 us; speedup vs baseline: 1.6924x; 1.3983x over previous
//
#include <hip/hip_runtime.h>
#include <math.h>

#define NN 16384      // nodes
#define E1N 65536     // edges level 1
#define NBATCH 256
#define NC2 65536     // clusters (level 2 and level 3)
#define KH 128        // edge-MLP hidden
#define OC 16         // o-chunk for M
#define NCOLS (KH*OC) // 2048
#define MSGPAD 136    // 128 + 8 f16 pad (breaks LDS bank alignment)

typedef _Float16 f16;
typedef _Float16 f16x2 __attribute__((ext_vector_type(2)));
typedef _Float16 f16x8 __attribute__((ext_vector_type(8)));
typedef float    f32x4 __attribute__((ext_vector_type(4)));

__device__ __forceinline__ float elu1(float x){ return x > 0.f ? x : expm1f(x); }

__device__ __forceinline__ float dot2acc(f16x2 a, f16x2 b, float c){
#if __has_builtin(__builtin_amdgcn_fdot2)
  return __builtin_amdgcn_fdot2(a, b, c, false);
#else
  return fmaf((float)a[0], (float)b[0], fmaf((float)a[1], (float)b[1], c));
#endif
}

// ---------------- CSR build (edges sorted by src) ----------------
__global__ __launch_bounds__(256) void k_deg(const int* __restrict__ ei, int* __restrict__ deg){
  int e = blockIdx.x*256 + threadIdx.x;
  if (e < E1N) atomicAdd(&deg[ei[e]], 1);
}

__global__ __launch_bounds__(256) void k_scan(const int* __restrict__ deg,
    int* __restrict__ cursor, int* __restrict__ rowptr){
  __shared__ int buf[256];
  __shared__ int carry;
  if (threadIdx.x == 0) carry = 0;
  __syncthreads();
  for (int base = 0; base < NN; base += 256){
    int v = deg[base + threadIdx.x];
    buf[threadIdx.x] = v; __syncthreads();
    for (int o = 1; o < 256; o <<= 1){
      int t = (threadIdx.x >= o) ? buf[threadIdx.x - o] : 0;
      __syncthreads();
      buf[threadIdx.x] += t;
      __syncthreads();
    }
    int incl = buf[threadIdx.x];
    int st = carry + incl - v;
    cursor[base + threadIdx.x] = st;
    rowptr[base + threadIdx.x] = st;
    __syncthreads();
    if (threadIdx.x == 255) carry += incl;
    __syncthreads();
  }
}

__global__ __launch_bounds__(256) void k_fill(const int* __restrict__ ei, int* __restrict__ cursor,
    int* __restrict__ eids, int* __restrict__ dsts){
  int e = blockIdx.x*256 + threadIdx.x;
  if (e >= E1N) return;
  int s = ei[e];
  int p = atomicAdd(&cursor[s], 1);
  eids[p] = e; dsts[p] = ei[E1N + e];
}

// ---------------- small converts ----------------
__global__ __launch_bounds__(256) void k_cvt16(const float* __restrict__ v, f16* __restrict__ o, int n){
  int t = blockIdx.x*256 + threadIdx.x;
  if (t < n) o[t] = (f16)v[t];
}

__global__ __launch_bounds__(256) void k_elu_both(float* __restrict__ v, f16* __restrict__ v16, int n){
  int t = blockIdx.x*256 + threadIdx.x;
  if (t < n){ float r = elu1(v[t]); v[t] = r; v16[t] = (f16)r; }
}

__global__ __launch_bounds__(256) void k_elu(float* __restrict__ v, int n){
  int t = blockIdx.x*256 + threadIdx.x;
  if (t < n) v[t] = elu1(v[t]);
}

// ---------------- NNConv pieces ----------------
// hrelu[p,k] (sorted edge order) = relu(b1[k] + sum_i ea[eids[p],i]*W1[i,k])
__global__ __launch_bounds__(256) void k_edge_mlp(const float* __restrict__ ea,
    const int* __restrict__ eids,
    const float* __restrict__ W1, const float* __restrict__ b1,
    f16* __restrict__ hrelu){
  int t = blockIdx.x*256 + threadIdx.x;
  if (t >= E1N*KH) return;
  int p = t >> 7, k = t & 127;
  const float* row = ea + (size_t)eids[p]*7;
  float acc = b1[k];
  #pragma unroll
  for (int i=0;i<7;i++) acc = fmaf(row[i], W1[i*KH+k], acc);
  hrelu[t] = (f16)fmaxf(acc, 0.f);
}

// outb[n,o] = bias[o] + sum_i x[n,i]*root[i,o] ; bterm[n,o] = sum_i x[n,i]*b2[i,o]
__global__ __launch_bounds__(256) void k_prep(const float* __restrict__ x,
    const float* __restrict__ root, const float* __restrict__ bias,
    const float* __restrict__ b2, float* __restrict__ outb, float* __restrict__ bterm,
    int mi, int mo){
  int t = blockIdx.x*256 + threadIdx.x;
  if (t >= NN*mo) return;
  int n = t / mo, o = t - n*mo;
  const float* xr = x + (size_t)n*mi;
  float a0 = bias[o], a1 = 0.f;
  for (int i=0;i<mi;i++){ float xv = xr[i]; a0 = fmaf(xv, root[i*mo+o], a0); a1 = fmaf(xv, b2[i*mo+o], a1); }
  outb[t] = a0; bterm[t] = a1;
}

// pack W2 chunk into MFMA B-fragment order, with block-col meaning remapped so that
// global Mc layout per node is [oc][k]  (col j' = oc*128 + kout):
// Bp[((q*S+s)*64 + l)*8 + j] with q = oc*8 + c, kout = c*16 + (l&15)
__global__ __launch_bounds__(256) void k_w2pack(const float* __restrict__ W2,
    f16* __restrict__ Bp, int mi, int mo, int ob, int S){
  int t = blockIdx.x*256 + threadIdx.x;
  if (t >= 128*S*512) return;
  int j = t & 7, l = (t >> 3) & 63, cs = t >> 9;
  int s = cs % S, q = cs / S;
  int oc = q >> 3, c = q & 7;
  int i = s*32 + ((l>>4)<<3) + j;
  int kout = (c<<4) + (l & 15);
  float v = (i < mi) ? W2[(size_t)kout*mi*mo + (size_t)i*mo + ob + oc] : 0.f;
  Bp[t] = (f16)v;
}

// Mc[16384 x 2048] = A[16384 x MI] @ B[MI x 2048] via MFMA, fp16 out, LDS-repacked stores
template<int MI, int S>
__global__ __launch_bounds__(256) void k_mgemm_mfma(const f16* __restrict__ A,
    const f16* __restrict__ Bp, f16* __restrict__ Mc){
  __shared__ __align__(16) f16 tile[64*128];   // 16 KB
  int l = threadIdx.x & 63, w = threadIdx.x >> 6;
  int r0 = blockIdx.x*64 + w*16;
  int cb = blockIdx.y*8;
  const f16* arow = A + (size_t)(r0 + (l & 15))*MI;
  f16x8 a[S];
  #pragma unroll
  for (int s=0;s<S;s++){
    int koff = s*32 + ((l>>4)<<3);
    if (koff < MI) a[s] = *(const f16x8*)(arow + koff);
    else           a[s] = (f16x8){0,0,0,0,0,0,0,0};
  }
  f32x4 acc[8];
  #pragma unroll
  for (int c=0;c<8;c++) acc[c] = (f32x4){0.f,0.f,0.f,0.f};
  #pragma unroll
  for (int c=0;c<8;c++){
    #pragma unroll
    for (int s=0;s<S;s++){
      f16x8 b = *(const f16x8*)(Bp + ((size_t)((cb + c)*S + s)*64 + l)*8);
      acc[c] = __builtin_amdgcn_mfma_f32_16x16x32_f16(a[s], b, acc[c], 0, 0, 0);
    }
  }
  f16* tw = tile + w*16*128;
  #pragma unroll
  for (int c=0;c<8;c++)
    #pragma unroll
    for (int r=0;r<4;r++)
      tw[(((l>>4)<<2) + r)*128 + c*16 + (l&15)] = (f16)acc[c][r];
  __syncthreads();
  // coalesced stores: 64 rows x 256 B
  int rr = threadIdx.x >> 2, q = threadIdx.x & 3;
  const uint4* sl = (const uint4*)tile;
  uint4* dst = (uint4*)Mc;
  size_t rowbase = (size_t)(blockIdx.x*64 + rr)*256 + blockIdx.y*16;
  #pragma unroll
  for (int i=0;i<4;i++)
    dst[rowbase + q*4 + i] = sl[rr*16 + q*4 + i];
}

// node-centric msg: one wave per node. Mc row [16 oc][128 k] -> LDS (coalesced),
// edges in groups of 4: lane = (eslot = l>>4, oc = l&15), K=128 dot2 reduction.
__global__ __launch_bounds__(256) void k_msg_node(const int* __restrict__ rowptr,
    const int* __restrict__ rowend, const int* __restrict__ dsts,
    const f16* __restrict__ hrelu, const f16* __restrict__ Mc,
    const float* __restrict__ bterm, float* __restrict__ outb, int mo, int ob){
  __shared__ __align__(16) f16 McL[4][16*MSGPAD];  // 17408 B
  __shared__ __align__(16) f16 hb[4][4*MSGPAD];    //  4352 B
  int l = threadIdx.x & 63, w = threadIdx.x >> 6;
  int n = blockIdx.x*4 + w;
  int start = rowptr[n], end = rowend[n];
  if (start >= end) return;   // wave-uniform
  // load 4KB Mc row coalesced: 4 x (64 lanes x 16B)
  const f16x8* gm = (const f16x8*)(Mc + (size_t)n*NCOLS);
  #pragma unroll
  for (int i=0;i<4;i++){
    int ci = i*64 + l;                 // chunk index within row
    f16x8 v = gm[ci];
    int oc_ = ci >> 4, k0 = (ci & 15)*8;
    *(f16x8*)&McL[w][oc_*MSGPAD + k0] = v;
  }
  int er = l >> 4, oc = l & 15;
  float bt = bterm[(size_t)n*mo + ob + oc];
  for (int e0 = start; e0 < end; e0 += 4){
    int ecnt = end - e0; if (ecnt > 4) ecnt = 4;
    if (er < ecnt){
      f16x8 hv = *(const f16x8*)(hrelu + (size_t)(e0+er)*KH + oc*8);
      *(f16x8*)&hb[w][er*MSGPAD + oc*8] = hv;
    }
    // in-wave LDS producer->consumer: wave64 is lockstep; drain LDS queue
    __asm__ volatile("s_waitcnt lgkmcnt(0)" ::: "memory");
    if (er < ecnt){
      float acc = bt;
      #pragma unroll 4
      for (int kk=0; kk<16; kk++){
        f16x8 m8 = *(const f16x8*)&McL[w][oc*MSGPAD + kk*8];
        f16x8 h8 = *(const f16x8*)&hb[w][er*MSGPAD + kk*8];
        #pragma unroll
        for (int j=0;j<4;j++){
          f16x2 hp = {h8[2*j], h8[2*j+1]};
          f16x2 mp = {m8[2*j], m8[2*j+1]};
          acc = dot2acc(hp, mp, acc);
        }
      }
      int d = dsts[e0 + er];
      atomicAdd(&outb[(size_t)d*mo + ob + oc], acc);
    }
  }
}

// ---------------- pooling / GraphConv ----------------
__global__ __launch_bounds__(256) void k_pool(const int* __restrict__ nodei,
    const int* __restrict__ clusteri, const float* __restrict__ h,
    float* __restrict__ pool, float* __restrict__ cnt, int A){
  int t = blockIdx.x*256 + threadIdx.x;
  if (t >= A*64) return;
  int a = t >> 6, f = t & 63;
  int c = clusteri[a], nd = nodei[a];
  atomicAdd(&pool[c*64+f], h[nd*64+f]);
  if (f==0) atomicAdd(&cnt[c], 1.f);
}

__global__ __launch_bounds__(256) void k_buildh16(const float* __restrict__ pool,
    const float* __restrict__ cnt, const float* __restrict__ iso,
    f16* __restrict__ h16){
  int t = blockIdx.x*256 + threadIdx.x;
  if (t >= NC2*128) return;
  int c = t >> 7, f = t & 127;
  float v = (f < 64) ? pool[c*64+f] / fmaxf(cnt[c], 1.f) : iso[(size_t)c*64 + (f-64)];
  h16[t] = (f16)v;
}

// pack [Wrel | Wroot] (each K x 64 fp32) into B-frag order, N=128
__global__ __launch_bounds__(256) void k_packB_gc(const float* __restrict__ Wrel,
    const float* __restrict__ Wroot, f16* __restrict__ Bp, int S){
  int t = blockIdx.x*256 + threadIdx.x;
  if (t >= 8*S*512) return;
  int j = t & 7, l = (t >> 3) & 63, cs = t >> 9;
  int s = cs % S, c = cs / S;
  int k = s*32 + ((l>>4)<<3) + j;
  int n = (c<<4) + (l & 15);
  float v = (n < 64) ? Wrel[k*64 + n] : Wroot[k*64 + (n - 64)];
  Bp[t] = (f16)v;
}

// [65536 x K] @ [K x 128] -> y (cols 0:64, fp32), outb (cols 64:128, +bias, fp32)
template<int S>
__global__ __launch_bounds__(256) void k_gc_mfma(const f16* __restrict__ A,
    const f16* __restrict__ Bp, const float* __restrict__ bias,
    float* __restrict__ y, float* __restrict__ outb){
  int l = threadIdx.x & 63, w = threadIdx.x >> 6;
  int r0 = blockIdx.x*64 + w*16;
  const f16* arow = A + (size_t)(r0 + (l & 15))*(S*32);
  f16x8 a[S];
  #pragma unroll
  for (int s=0;s<S;s++) a[s] = *(const f16x8*)(arow + s*32 + ((l>>4)<<3));
  f32x4 acc[8];
  #pragma unroll
  for (int c=0;c<8;c++) acc[c] = (f32x4){0.f,0.f,0.f,0.f};
  #pragma unroll
  for (int c=0;c<8;c++){
    #pragma unroll
    for (int s=0;s<S;s++){
      f16x8 b = *(const f16x8*)(Bp + ((size_t)(c*S + s)*64 + l)*8);
      acc[c] = __builtin_amdgcn_mfma_f32_16x16x32_f16(a[s], b, acc[c], 0, 0, 0);
    }
  }
  #pragma unroll
  for (int c=0;c<8;c++){
    int col = c*16 + (l & 15);
    #pragma unroll
    for (int r=0;r<4;r++){
      int row = r0 + ((l>>4)<<2) + r;
      if (col < 64) y[(size_t)row*64 + col] = acc[c][r];
      else          outb[(size_t)row*64 + (col-64)] = acc[c][r] + bias[col-64];
    }
  }
}

__global__ __launch_bounds__(256) void k_gc_scatter(const int* __restrict__ src,
    const int* __restrict__ dst, const float* __restrict__ y,
    float* __restrict__ outb, int E){
  int t = blockIdx.x*256 + threadIdx.x;
  if (t >= E*64) return;
  int e = t >> 6, o = t & 63;
  atomicAdd(&outb[(size_t)dst[e]*64 + o], y[(size_t)src[e]*64 + o]);
}

__global__ __launch_bounds__(256) void k_batchsum(const int* __restrict__ b,
    const float* __restrict__ h, float* __restrict__ x123, int Nc, int off){
  int t = blockIdx.x*256 + threadIdx.x;
  if (t >= Nc*64) return;
  int n = t >> 6, f = t & 63;
  atomicAdd(&x123[b[n]*192 + off + f], h[t]);
}

// ---------------- FC head ----------------
__global__ __launch_bounds__(256) void k_fc1(const float* __restrict__ x123,
    const float* __restrict__ W, const float* __restrict__ b, float* __restrict__ t1){
  int t = blockIdx.x*256 + threadIdx.x;
  if (t >= NBATCH*64) return;
  int bb = t >> 6, o = t & 63;
  const float* xr = x123 + bb*192;
  float acc = b[o];
  for (int j=0;j<192;j++) acc = fmaf(xr[j], W[j*64+o] + W[(192+j)*64+o], acc);
  t1[t] = elu1(acc);
}

__global__ __launch_bounds__(256) void k_fc2(const float* __restrict__ t1,
    const float* __restrict__ W, const float* __restrict__ b, float* __restrict__ t2){
  int t = blockIdx.x*256 + threadIdx.x;
  if (t >= NBATCH*32) return;
  int bb = t >> 5, o = t & 31;
  float acc = b[o];
  for (int j=0;j<64;j++) acc = fmaf(t1[bb*64+j], W[j*32+o], acc);
  t2[t] = elu1(acc);
}

__global__ __launch_bounds__(256) void k_fc3(const float* __restrict__ t2,
    const float* __restrict__ W, const float* __restrict__ b, float* __restrict__ out){
  int t = blockIdx.x*256 + threadIdx.x;
  if (t >= NBATCH) return;
  float acc = b[0];
  for (int j=0;j<32;j++) acc = fmaf(t2[t*32+j], W[j], acc);
  out[t] = acc;
}

static inline int cdiv(long long a, int b){ return (int)((a + b - 1) / b); }

extern "C" void kernel_launch(void* const* d_in, const int* in_sizes, int n_in,
                              void* d_out, int out_size, void* d_ws, size_t ws_size,
                              hipStream_t stream) {
  const float* x0    = (const float*)d_in[0];
  const int*   ei    = (const int*)d_in[1];
  const float* ea    = (const float*)d_in[2];
  const int*   batch = (const int*)d_in[3];
  const int*   a2n   = (const int*)d_in[4];
  const int*   a2c   = (const int*)d_in[5];
  const float* iso2  = (const float*)d_in[6];
  const int*   ei2   = (const int*)d_in[7];
  const int*   b2arr = (const int*)d_in[8];
  const int*   a3n   = (const int*)d_in[9];
  const int*   a3c   = (const int*)d_in[10];
  const float* iso3  = (const float*)d_in[11];
  const int*   ei3   = (const int*)d_in[12];
  const int*   b3arr = (const int*)d_in[13];
  const float* nnp[3][6];
  for (int c=0;c<3;c++) for (int p=0;p<6;p++) nnp[c][p] = (const float*)d_in[14 + 6*c + p];
  const float* c4W[3]; const float* c5W[3]; const float* c6W[3]; const float* c7W[3];
  for (int p=0;p<3;p++){ c4W[p]=(const float*)d_in[32+p]; c5W[p]=(const float*)d_in[35+p];
                         c6W[p]=(const float*)d_in[38+p]; c7W[p]=(const float*)d_in[41+p]; }
  const float* fc1W=(const float*)d_in[44]; const float* fc1b=(const float*)d_in[45];
  const float* fc2W=(const float*)d_in[46]; const float* fc2b=(const float*)d_in[47];
  const float* fc3W=(const float*)d_in[48]; const float* fc3b=(const float*)d_in[49];
  float* outp = (float*)d_out;

  // ---- workspace carve ----
  char* ws = (char*)d_ws; size_t off = 0;
  auto alloc = [&](size_t bytes)->void*{ void* p = ws + off; off += (bytes + 255) & ~(size_t)255; return p; };
  const size_t SZ_R0 = (size_t)92*1024*1024;
  char* r0 = (char*)alloc(SZ_R0);
  // phase-1 view (NNConv):  hrelu 16MB | Mc 64MB | W2p 256KB | bterm 4MB
  f16*   hrelu = (f16*)r0;
  f16*   Mc    = (f16*)(r0 + (size_t)E1N*KH*2);
  f16*   W2p   = (f16*)(r0 + (size_t)E1N*KH*2 + (size_t)NN*NCOLS*2);
  float* bterm = (float*)(r0 + (size_t)E1N*KH*2 + (size_t)NN*NCOLS*2 + 256*1024);
  // phase-2 view (levels): pool 16MB | cnt .25MB | ybuf 16MB | gA 16MB | gB 16MB | h16 16MB | g16 8MB | BpGc 32KB
  float* pool = (float*)r0;
  float* cnt  = (float*)(r0 + (size_t)NC2*64*4);
  float* ybuf = (float*)(r0 + (size_t)NC2*65*4);
  float* gA   = (float*)(r0 + (size_t)NC2*(65+64)*4);
  float* gB   = (float*)(r0 + (size_t)NC2*(65+128)*4);
  f16*   h16  = (f16*)  (r0 + (size_t)NC2*(65+192)*4);
  f16*   g16  = (f16*)  (r0 + (size_t)NC2*(65+192)*4 + (size_t)NC2*128*2);
  f16*   BpGc = (f16*)  (r0 + (size_t)NC2*(65+192)*4 + (size_t)NC2*192*2);
  // persistent
  float* hA    = (float*)alloc((size_t)NN*32*4);
  float* hB    = (float*)alloc((size_t)NN*64*4);
  float* hC    = (float*)alloc((size_t)NN*64*4);
  f16*   x016  = (f16*)  alloc((size_t)NN*16*2);
  f16*   hA16  = (f16*)  alloc((size_t)NN*32*2);
  f16*   hB16  = (f16*)  alloc((size_t)NN*64*2);
  int*   deg   = (int*)  alloc((size_t)NN*4);
  int*   cursor= (int*)  alloc((size_t)NN*4);
  int*   rowptr= (int*)  alloc((size_t)NN*4);
  int*   eids  = (int*)  alloc((size_t)E1N*4);
  int*   dsts  = (int*)  alloc((size_t)E1N*4);
  float* x123  = (float*)alloc((size_t)NBATCH*192*4);
  float* t1    = (float*)alloc((size_t)NBATCH*64*4);
  float* t2    = (float*)alloc((size_t)NBATCH*32*4);
  (void)ws_size; (void)n_in; (void)in_sizes; (void)out_size;

  // ---- CSR: sort edges by src (once; reused by all 3 convs) ----
  hipMemsetAsync(deg, 0, (size_t)NN*4, stream);
  k_deg<<<cdiv(E1N,256),256,0,stream>>>(ei, deg);
  k_scan<<<1,256,0,stream>>>(deg, cursor, rowptr);
  k_fill<<<cdiv(E1N,256),256,0,stream>>>(ei, cursor, eids, dsts);
  k_cvt16<<<cdiv((long long)NN*16,256),256,0,stream>>>(x0, x016, NN*16);

  // ---- NNConv x3 ----
  auto run_nnconv = [&](const float* xin, const f16* xin16, int mi, int mo,
                        const float* const* P, float* outb, f16* out16){
    const float* W1=P[0]; const float* b1=P[1]; const float* W2=P[2];
    const float* b2=P[3]; const float* root=P[4]; const float* bias=P[5];
    k_edge_mlp<<<cdiv((long long)E1N*KH,256),256,0,stream>>>(ea, eids, W1, b1, hrelu);
    k_prep<<<cdiv((long long)NN*mo,256),256,0,stream>>>(xin, root, bias, b2, outb, bterm, mi, mo);
    const int S = (mi > 32) ? 2 : 1;
    for (int ob = 0; ob < mo; ob += OC){
      k_w2pack<<<cdiv((long long)128*S*512,256),256,0,stream>>>(W2, W2p, mi, mo, ob, S);
      dim3 g(NN/64, NCOLS/128);
      if (mi==16)      k_mgemm_mfma<16,1><<<g,256,0,stream>>>(xin16, W2p, Mc);
      else if (mi==32) k_mgemm_mfma<32,1><<<g,256,0,stream>>>(xin16, W2p, Mc);
      else             k_mgemm_mfma<64,2><<<g,256,0,stream>>>(xin16, W2p, Mc);
      k_msg_node<<<NN/4,256,0,stream>>>(rowptr, cursor, dsts, hrelu, Mc, bterm, outb, mo, ob);
    }
    k_elu_both<<<cdiv((long long)NN*mo,256),256,0,stream>>>(outb, out16, NN*mo);
  };
  run_nnconv(x0, x016, 16, 32, nnp[0], hA, hA16);
  run_nnconv(hA, hA16, 32, 64, nnp[1], hB, hB16);
  run_nnconv(hB, hB16, 64, 64, nnp[2], hC, hB16 /*unused after*/);

  hipMemsetAsync(x123, 0, (size_t)NBATCH*192*4, stream);
  k_batchsum<<<cdiv((long long)NN*64,256),256,0,stream>>>(batch, hC, x123, NN, 0);

  // ---- levels 2 and 3 ----
  auto run_level = [&](const int* an, const int* ac, int A, const float* iso,
                       const int* eiL, int EL, const int* batchL,
                       const float* const* cA, const float* const* cB, int off123){
    hipMemsetAsync(pool, 0, (size_t)NC2*64*4, stream);
    hipMemsetAsync(cnt, 0, (size_t)NC2*4, stream);
    k_pool<<<cdiv((long long)A*64,256),256,0,stream>>>(an, ac, hC, pool, cnt, A);
    k_buildh16<<<cdiv((long long)NC2*128,256),256,0,stream>>>(pool, cnt, iso, h16);
    k_packB_gc<<<cdiv((long long)8*4*512,256),256,0,stream>>>(cA[0], cA[1], BpGc, 4);
    k_gc_mfma<4><<<NC2/64,256,0,stream>>>(h16, BpGc, cA[2], ybuf, gA);
    k_gc_scatter<<<cdiv((long long)EL*64,256),256,0,stream>>>(eiL, eiL+EL, ybuf, gA, EL);
    k_elu_both<<<cdiv((long long)NC2*64,256),256,0,stream>>>(gA, g16, NC2*64);
    k_packB_gc<<<cdiv((long long)8*2*512,256),256,0,stream>>>(cB[0], cB[1], BpGc, 2);
    k_gc_mfma<2><<<NC2/64,256,0,stream>>>(g16, BpGc, cB[2], ybuf, gB);
    k_gc_scatter<<<cdiv((long long)EL*64,256),256,0,stream>>>(eiL, eiL+EL, ybuf, gB, EL);
    k_elu<<<cdiv((long long)NC2*64,256),256,0,stream>>>(gB, NC2*64);
    k_batchsum<<<cdiv((long long)NC2*64,256),256,0,stream>>>(batchL, gB, x123, NC2, off123);
  };
  run_level(a2n, a2c, 131072, iso2, ei2, 262144, b2arr, c4W, c5W, 64);
  run_level(a3n, a3c, 196608, iso3, ei3, 262144, b3arr, c6W, c7W, 128);

  // ---- FC head ----
  k_fc1<<<cdiv((long long)NBATCH*64,256),256,0,stream>>>(x123, fc1W, fc1b, t1);
  k_fc2<<<cdiv((long long)NBATCH*32,256),256,0,stream>>>(t1, fc2W, fc2b, t2);
  k_fc3<<<cdiv(NBATCH,256),256,0,stream>>>(t2, fc3W, fc3b, outp);
}

// Round 5
// 1241.185 us; speedup vs baseline: 2.0273x; 1.1979x over previous
//
#include <hip/hip_runtime.h>
#include <math.h>

#define NN 16384      // nodes
#define E1N 65536     // edges level 1
#define NBATCH 256
#define NC2 65536     // clusters (level 2 and level 3)
#define KH 128        // edge-MLP hidden
#define OC 16         // o-chunk for M
#define NCOLS (KH*OC) // 2048
#define MSGPAD 136    // 128 + 8 f16 pad

typedef _Float16 f16;
typedef _Float16 f16x2 __attribute__((ext_vector_type(2)));
typedef _Float16 f16x8 __attribute__((ext_vector_type(8)));
typedef float    f32x4 __attribute__((ext_vector_type(4)));

__device__ __forceinline__ float elu1(float x){ return x > 0.f ? x : expm1f(x); }

__device__ __forceinline__ float dot2acc(f16x2 a, f16x2 b, float c){
#if __has_builtin(__builtin_amdgcn_fdot2)
  return __builtin_amdgcn_fdot2(a, b, c, false);
#else
  return fmaf((float)a[0], (float)b[0], fmaf((float)a[1], (float)b[1], c));
#endif
}

// ---------------- generic counting + 3-phase scan ----------------
__global__ __launch_bounds__(256) void k_count(const int* __restrict__ arr, int* __restrict__ cnt, int n){
  int i = blockIdx.x*256 + threadIdx.x;
  if (i < n) atomicAdd(&cnt[arr[i]], 1);
}

// phase 1: block-local exclusive scan; block total -> partials
__global__ __launch_bounds__(256) void k_scan1(const int* __restrict__ deg,
    int* __restrict__ ptr, int* __restrict__ partials){
  __shared__ int buf[256];
  int i = blockIdx.x*256 + threadIdx.x, t = threadIdx.x;
  int v = deg[i];
  buf[t] = v; __syncthreads();
  for (int o = 1; o < 256; o <<= 1){
    int x = (t >= o) ? buf[t-o] : 0;
    __syncthreads(); buf[t] += x; __syncthreads();
  }
  ptr[i] = buf[t] - v;
  if (t == 255) partials[blockIdx.x] = buf[255];
}

// phase 2: single block, exclusive scan of partials (nb <= 256)
__global__ __launch_bounds__(256) void k_scan2(int* __restrict__ partials, int nb){
  __shared__ int buf[256];
  int t = threadIdx.x;
  int v = (t < nb) ? partials[t] : 0;
  buf[t] = v; __syncthreads();
  for (int o = 1; o < 256; o <<= 1){
    int x = (t >= o) ? buf[t-o] : 0;
    __syncthreads(); buf[t] += x; __syncthreads();
  }
  if (t < nb) partials[t] = buf[t] - v;
}

// phase 3: add block offset; duplicate into cursor
__global__ __launch_bounds__(256) void k_scan3(const int* __restrict__ partials,
    int* __restrict__ ptr, int* __restrict__ cur){
  int i = blockIdx.x*256 + threadIdx.x;
  int v = ptr[i] + partials[blockIdx.x];
  ptr[i] = v; cur[i] = v;
}

// ---------------- CSR fills ----------------
__global__ __launch_bounds__(256) void k_fill_edge(const int* __restrict__ ei, int* __restrict__ cursor,
    int* __restrict__ eids, int* __restrict__ dsts){
  int e = blockIdx.x*256 + threadIdx.x;
  if (e >= E1N) return;
  int s = ei[e];
  int p = atomicAdd(&cursor[s], 1);
  eids[p] = e; dsts[p] = ei[E1N + e];
}

__global__ __launch_bounds__(256) void k_fill_dst(const int* __restrict__ eiL, int* __restrict__ cur,
    int* __restrict__ dsrc, int EL){
  int e = blockIdx.x*256 + threadIdx.x;
  if (e >= EL) return;
  int d = eiL[EL + e];
  int p = atomicAdd(&cur[d], 1);
  dsrc[p] = eiL[e];
}

__global__ __launch_bounds__(256) void k_fill_assign(const int* __restrict__ an, const int* __restrict__ ac,
    int* __restrict__ cur, int* __restrict__ an_sorted, int A){
  int a = blockIdx.x*256 + threadIdx.x;
  if (a >= A) return;
  int c = ac[a];
  int p = atomicAdd(&cur[c], 1);
  an_sorted[p] = an[a];
}

// ---------------- small converts ----------------
__global__ __launch_bounds__(256) void k_cvt16(const float* __restrict__ v, f16* __restrict__ o, int n){
  int t = blockIdx.x*256 + threadIdx.x;
  if (t < n) o[t] = (f16)v[t];
}

__global__ __launch_bounds__(256) void k_elu_both(float* __restrict__ v, f16* __restrict__ v16, int n){
  int t = blockIdx.x*256 + threadIdx.x;
  if (t < n){ float r = elu1(v[t]); v[t] = r; v16[t] = (f16)r; }
}

__global__ __launch_bounds__(256) void k_elu(float* __restrict__ v, int n){
  int t = blockIdx.x*256 + threadIdx.x;
  if (t < n) v[t] = elu1(v[t]);
}

// ---------------- NNConv pieces ----------------
__global__ __launch_bounds__(256) void k_edge_mlp(const float* __restrict__ ea,
    const int* __restrict__ eids,
    const float* __restrict__ W1, const float* __restrict__ b1,
    f16* __restrict__ hrelu){
  int t = blockIdx.x*256 + threadIdx.x;
  if (t >= E1N*KH) return;
  int p = t >> 7, k = t & 127;
  const float* row = ea + (size_t)eids[p]*7;
  float acc = b1[k];
  #pragma unroll
  for (int i=0;i<7;i++) acc = fmaf(row[i], W1[i*KH+k], acc);
  hrelu[t] = (f16)fmaxf(acc, 0.f);
}

__global__ __launch_bounds__(256) void k_prep(const float* __restrict__ x,
    const float* __restrict__ root, const float* __restrict__ bias,
    const float* __restrict__ b2, float* __restrict__ outb, float* __restrict__ bterm,
    int mi, int mo){
  int t = blockIdx.x*256 + threadIdx.x;
  if (t >= NN*mo) return;
  int n = t / mo, o = t - n*mo;
  const float* xr = x + (size_t)n*mi;
  float a0 = bias[o], a1 = 0.f;
  for (int i=0;i<mi;i++){ float xv = xr[i]; a0 = fmaf(xv, root[i*mo+o], a0); a1 = fmaf(xv, b2[i*mo+o], a1); }
  outb[t] = a0; bterm[t] = a1;
}

// pack W2 chunk into MFMA B-frag order; Mc per-node layout is [oc][k]
__global__ __launch_bounds__(256) void k_w2pack(const float* __restrict__ W2,
    f16* __restrict__ Bp, int mi, int mo, int ob, int S){
  int t = blockIdx.x*256 + threadIdx.x;
  if (t >= 128*S*512) return;
  int j = t & 7, l = (t >> 3) & 63, cs = t >> 9;
  int s = cs % S, q = cs / S;
  int oc = q >> 3, c = q & 7;
  int i = s*32 + ((l>>4)<<3) + j;
  int kout = (c<<4) + (l & 15);
  float v = (i < mi) ? W2[(size_t)kout*mi*mo + (size_t)i*mo + ob + oc] : 0.f;
  Bp[t] = (f16)v;
}

template<int MI, int S>
__global__ __launch_bounds__(256) void k_mgemm_mfma(const f16* __restrict__ A,
    const f16* __restrict__ Bp, f16* __restrict__ Mc){
  __shared__ __align__(16) f16 tile[64*128];
  int l = threadIdx.x & 63, w = threadIdx.x >> 6;
  int r0 = blockIdx.x*64 + w*16;
  int cb = blockIdx.y*8;
  const f16* arow = A + (size_t)(r0 + (l & 15))*MI;
  f16x8 a[S];
  #pragma unroll
  for (int s=0;s<S;s++){
    int koff = s*32 + ((l>>4)<<3);
    if (koff < MI) a[s] = *(const f16x8*)(arow + koff);
    else           a[s] = (f16x8){0,0,0,0,0,0,0,0};
  }
  f32x4 acc[8];
  #pragma unroll
  for (int c=0;c<8;c++) acc[c] = (f32x4){0.f,0.f,0.f,0.f};
  #pragma unroll
  for (int c=0;c<8;c++){
    #pragma unroll
    for (int s=0;s<S;s++){
      f16x8 b = *(const f16x8*)(Bp + ((size_t)((cb + c)*S + s)*64 + l)*8);
      acc[c] = __builtin_amdgcn_mfma_f32_16x16x32_f16(a[s], b, acc[c], 0, 0, 0);
    }
  }
  f16* tw = tile + w*16*128;
  #pragma unroll
  for (int c=0;c<8;c++)
    #pragma unroll
    for (int r=0;r<4;r++)
      tw[(((l>>4)<<2) + r)*128 + c*16 + (l&15)] = (f16)acc[c][r];
  __syncthreads();
  int rr = threadIdx.x >> 2, q = threadIdx.x & 3;
  const uint4* sl = (const uint4*)tile;
  uint4* dst = (uint4*)Mc;
  size_t rowbase = (size_t)(blockIdx.x*64 + rr)*256 + blockIdx.y*16;
  #pragma unroll
  for (int i=0;i<4;i++)
    dst[rowbase + q*4 + i] = sl[rr*16 + q*4 + i];
}

// node-centric msg: one wave per node
__global__ __launch_bounds__(256) void k_msg_node(const int* __restrict__ rowptr,
    const int* __restrict__ rowend, const int* __restrict__ dsts,
    const f16* __restrict__ hrelu, const f16* __restrict__ Mc,
    const float* __restrict__ bterm, float* __restrict__ outb, int mo, int ob){
  __shared__ __align__(16) f16 McL[4][16*MSGPAD];
  __shared__ __align__(16) f16 hb[4][4*MSGPAD];
  int l = threadIdx.x & 63, w = threadIdx.x >> 6;
  int n = blockIdx.x*4 + w;
  int start = rowptr[n], end = rowend[n];
  if (start >= end) return;
  const f16x8* gm = (const f16x8*)(Mc + (size_t)n*NCOLS);
  #pragma unroll
  for (int i=0;i<4;i++){
    int ci = i*64 + l;
    f16x8 v = gm[ci];
    int oc_ = ci >> 4, k0 = (ci & 15)*8;
    *(f16x8*)&McL[w][oc_*MSGPAD + k0] = v;
  }
  int er = l >> 4, oc = l & 15;
  float bt = bterm[(size_t)n*mo + ob + oc];
  for (int e0 = start; e0 < end; e0 += 4){
    int ecnt = end - e0; if (ecnt > 4) ecnt = 4;
    if (er < ecnt){
      f16x8 hv = *(const f16x8*)(hrelu + (size_t)(e0+er)*KH + oc*8);
      *(f16x8*)&hb[w][er*MSGPAD + oc*8] = hv;
    }
    __asm__ volatile("s_waitcnt lgkmcnt(0)" ::: "memory");
    if (er < ecnt){
      float acc = bt;
      #pragma unroll 4
      for (int kk=0; kk<16; kk++){
        f16x8 m8 = *(const f16x8*)&McL[w][oc*MSGPAD + kk*8];
        f16x8 h8 = *(const f16x8*)&hb[w][er*MSGPAD + kk*8];
        #pragma unroll
        for (int j=0;j<4;j++){
          f16x2 hp = {h8[2*j], h8[2*j+1]};
          f16x2 mp = {m8[2*j], m8[2*j+1]};
          acc = dot2acc(hp, mp, acc);
        }
      }
      int d = dsts[e0 + er];
      atomicAdd(&outb[(size_t)d*mo + ob + oc], acc);
    }
  }
}

// ---------------- pooling via cluster-CSR (no atomics) ----------------
// one wave per cluster: h16[c,0:64] = mean over assigned nodes; h16[c,64:128] = iso
__global__ __launch_bounds__(256) void k_pool_gather(const int* __restrict__ aptr,
    const int* __restrict__ aend, const int* __restrict__ an_sorted,
    const float* __restrict__ h, const float* __restrict__ iso,
    f16* __restrict__ h16){
  int l = threadIdx.x & 63, w = threadIdx.x >> 6;
  int c = blockIdx.x*4 + w;
  int st = aptr[c], en = aend[c];
  float acc = 0.f;
  int e = st;
  for (; e+1 < en; e += 2){
    int n0 = an_sorted[e], n1 = an_sorted[e+1];
    acc += h[(size_t)n0*64 + l];
    acc += h[(size_t)n1*64 + l];
  }
  if (e < en) acc += h[(size_t)an_sorted[e]*64 + l];
  int cnt = en - st;
  float val = (cnt > 0) ? acc / (float)cnt : 0.f;
  h16[(size_t)c*128 + l] = (f16)val;
  h16[(size_t)c*128 + 64 + l] = (f16)iso[(size_t)c*64 + l];
}

// ---------------- GraphConv ----------------
__global__ __launch_bounds__(256) void k_packB_gc(const float* __restrict__ Wrel,
    const float* __restrict__ Wroot, f16* __restrict__ Bp, int S){
  int t = blockIdx.x*256 + threadIdx.x;
  if (t >= 8*S*512) return;
  int j = t & 7, l = (t >> 3) & 63, cs = t >> 9;
  int s = cs % S, c = cs / S;
  int k = s*32 + ((l>>4)<<3) + j;
  int n = (c<<4) + (l & 15);
  float v = (n < 64) ? Wrel[k*64 + n] : Wroot[k*64 + (n - 64)];
  Bp[t] = (f16)v;
}

// [65536 x K] @ [K x 128] -> y (rel, cols 0:64), rbuf (root+bias, cols 64:128)
template<int S>
__global__ __launch_bounds__(256) void k_gc_mfma(const f16* __restrict__ A,
    const f16* __restrict__ Bp, const float* __restrict__ bias,
    float* __restrict__ y, float* __restrict__ rbuf){
  int l = threadIdx.x & 63, w = threadIdx.x >> 6;
  int r0 = blockIdx.x*64 + w*16;
  const f16* arow = A + (size_t)(r0 + (l & 15))*(S*32);
  f16x8 a[S];
  #pragma unroll
  for (int s=0;s<S;s++) a[s] = *(const f16x8*)(arow + s*32 + ((l>>4)<<3));
  f32x4 acc[8];
  #pragma unroll
  for (int c=0;c<8;c++) acc[c] = (f32x4){0.f,0.f,0.f,0.f};
  #pragma unroll
  for (int c=0;c<8;c++){
    #pragma unroll
    for (int s=0;s<S;s++){
      f16x8 b = *(const f16x8*)(Bp + ((size_t)(c*S + s)*64 + l)*8);
      acc[c] = __builtin_amdgcn_mfma_f32_16x16x32_f16(a[s], b, acc[c], 0, 0, 0);
    }
  }
  #pragma unroll
  for (int c=0;c<8;c++){
    int col = c*16 + (l & 15);
    #pragma unroll
    for (int r=0;r<4;r++){
      int row = r0 + ((l>>4)<<2) + r;
      if (col < 64) y[(size_t)row*64 + col] = acc[c][r];
      else          rbuf[(size_t)row*64 + (col-64)] = acc[c][r] + bias[col-64];
    }
  }
}

// dst-CSR gather: out[n] = elu(rbuf[n] + sum_{e in row} y[dsrc[e]]); optional f16/f32 out
template<bool F16OUT>
__global__ __launch_bounds__(256) void k_gc_gather(const int* __restrict__ dptr,
    const int* __restrict__ dend, const int* __restrict__ dsrc,
    const float* __restrict__ y, const float* __restrict__ rbuf,
    f16* __restrict__ o16, float* __restrict__ o32){
  int l = threadIdx.x & 63, w = threadIdx.x >> 6;
  int n = blockIdx.x*4 + w;
  int st = dptr[n], en = dend[n];
  float acc = rbuf[(size_t)n*64 + l];
  int e = st;
  for (; e+1 < en; e += 2){
    int s0 = dsrc[e], s1 = dsrc[e+1];
    acc += y[(size_t)s0*64 + l];
    acc += y[(size_t)s1*64 + l];
  }
  if (e < en) acc += y[(size_t)dsrc[e]*64 + l];
  float r = elu1(acc);
  if (F16OUT) o16[(size_t)n*64 + l] = (f16)r;
  else        o32[(size_t)n*64 + l] = r;
}

// ---------------- sorted-segment batch sum (no atomics) ----------------
__device__ __forceinline__ int lowerb(const int* __restrict__ a, int n, int key){
  int lo = 0, hi = n;
  while (lo < hi){ int m = (lo + hi) >> 1; if (a[m] < key) lo = m + 1; else hi = m; }
  return lo;
}

__global__ __launch_bounds__(256) void k_batchsum_seg(const int* __restrict__ batch,
    const float* __restrict__ h, float* __restrict__ x123, int n_nodes, int off){
  __shared__ float red[4][64];
  int b = blockIdx.x;
  int lo = lowerb(batch, n_nodes, b);
  int hi = lowerb(batch, n_nodes, b+1);
  int col = threadIdx.x & 63, wq = threadIdx.x >> 6;
  float acc = 0.f;
  for (int n = lo + wq; n < hi; n += 4) acc += h[(size_t)n*64 + col];
  red[wq][col] = acc;
  __syncthreads();
  if (threadIdx.x < 64){
    float s = red[0][threadIdx.x] + red[1][threadIdx.x] + red[2][threadIdx.x] + red[3][threadIdx.x];
    x123[b*192 + off + threadIdx.x] = s;
  }
}

// ---------------- FC head ----------------
__global__ __launch_bounds__(256) void k_fc1(const float* __restrict__ x123,
    const float* __restrict__ W, const float* __restrict__ b, float* __restrict__ t1){
  int t = blockIdx.x*256 + threadIdx.x;
  if (t >= NBATCH*64) return;
  int bb = t >> 6, o = t & 63;
  const float* xr = x123 + bb*192;
  float acc = b[o];
  for (int j=0;j<192;j++) acc = fmaf(xr[j], W[j*64+o] + W[(192+j)*64+o], acc);
  t1[t] = elu1(acc);
}

__global__ __launch_bounds__(256) void k_fc2(const float* __restrict__ t1,
    const float* __restrict__ W, const float* __restrict__ b, float* __restrict__ t2){
  int t = blockIdx.x*256 + threadIdx.x;
  if (t >= NBATCH*32) return;
  int bb = t >> 5, o = t & 31;
  float acc = b[o];
  for (int j=0;j<64;j++) acc = fmaf(t1[bb*64+j], W[j*32+o], acc);
  t2[t] = elu1(acc);
}

__global__ __launch_bounds__(256) void k_fc3(const float* __restrict__ t2,
    const float* __restrict__ W, const float* __restrict__ b, float* __restrict__ out){
  int t = blockIdx.x*256 + threadIdx.x;
  if (t >= NBATCH) return;
  float acc = b[0];
  for (int j=0;j<32;j++) acc = fmaf(t2[t*32+j], W[j], acc);
  out[t] = acc;
}

static inline int cdiv(long long a, int b){ return (int)((a + b - 1) / b); }

extern "C" void kernel_launch(void* const* d_in, const int* in_sizes, int n_in,
                              void* d_out, int out_size, void* d_ws, size_t ws_size,
                              hipStream_t stream) {
  const float* x0    = (const float*)d_in[0];
  const int*   ei    = (const int*)d_in[1];
  const float* ea    = (const float*)d_in[2];
  const int*   batch = (const int*)d_in[3];
  const int*   a2n   = (const int*)d_in[4];
  const int*   a2c   = (const int*)d_in[5];
  const float* iso2  = (const float*)d_in[6];
  const int*   ei2   = (const int*)d_in[7];
  const int*   b2arr = (const int*)d_in[8];
  const int*   a3n   = (const int*)d_in[9];
  const int*   a3c   = (const int*)d_in[10];
  const float* iso3  = (const float*)d_in[11];
  const int*   ei3   = (const int*)d_in[12];
  const int*   b3arr = (const int*)d_in[13];
  const float* nnp[3][6];
  for (int c=0;c<3;c++) for (int p=0;p<6;p++) nnp[c][p] = (const float*)d_in[14 + 6*c + p];
  const float* c4W[3]; const float* c5W[3]; const float* c6W[3]; const float* c7W[3];
  for (int p=0;p<3;p++){ c4W[p]=(const float*)d_in[32+p]; c5W[p]=(const float*)d_in[35+p];
                         c6W[p]=(const float*)d_in[38+p]; c7W[p]=(const float*)d_in[41+p]; }
  const float* fc1W=(const float*)d_in[44]; const float* fc1b=(const float*)d_in[45];
  const float* fc2W=(const float*)d_in[46]; const float* fc2b=(const float*)d_in[47];
  const float* fc3W=(const float*)d_in[48]; const float* fc3b=(const float*)d_in[49];
  float* outp = (float*)d_out;

  // ---- workspace carve ----
  char* ws = (char*)d_ws; size_t off = 0;
  auto alloc = [&](size_t bytes)->void*{ void* p = ws + off; off += (bytes + 255) & ~(size_t)255; return p; };
  const size_t SZ_R0 = (size_t)92*1024*1024;
  char* r0 = (char*)alloc(SZ_R0);
  // phase-1 view (NNConv): hrelu 16MB | Mc 64MB | W2p 256KB | bterm 4MB
  f16*   hrelu = (f16*)r0;
  f16*   Mc    = (f16*)(r0 + (size_t)E1N*KH*2);
  f16*   W2p   = (f16*)(r0 + (size_t)E1N*KH*2 + (size_t)NN*NCOLS*2);
  float* bterm = (float*)(r0 + (size_t)E1N*KH*2 + (size_t)NN*NCOLS*2 + 256*1024);
  // phase-2 view (levels)
  size_t o2 = 0;
  auto a2 = [&](size_t bytes)->char*{ char* p = r0 + o2; o2 += (bytes + 255) & ~(size_t)255; return p; };
  f16*   h16   = (f16*)  a2((size_t)NC2*128*2);   // 16 MB
  float* ybuf  = (float*)a2((size_t)NC2*64*4);    // 16 MB
  float* rbuf  = (float*)a2((size_t)NC2*64*4);    // 16 MB
  float* gB    = (float*)a2((size_t)NC2*64*4);    // 16 MB
  f16*   g16   = (f16*)  a2((size_t)NC2*64*2);    //  8 MB
  f16*   BpGc  = (f16*)  a2((size_t)8*4*512*2);   // 32 KB
  int*   aptr  = (int*)  a2((size_t)NC2*4);
  int*   acur  = (int*)  a2((size_t)NC2*4);
  int*   dptr  = (int*)  a2((size_t)NC2*4);
  int*   dcur  = (int*)  a2((size_t)NC2*4);
  int*   ldeg  = (int*)  a2((size_t)NC2*4);
  int*   ans   = (int*)  a2((size_t)196608*4);
  int*   dsrc  = (int*)  a2((size_t)262144*4);
  // persistent
  float* hA    = (float*)alloc((size_t)NN*32*4);
  float* hB    = (float*)alloc((size_t)NN*64*4);
  float* hC    = (float*)alloc((size_t)NN*64*4);
  f16*   x016  = (f16*)  alloc((size_t)NN*16*2);
  f16*   hA16  = (f16*)  alloc((size_t)NN*32*2);
  f16*   hB16  = (f16*)  alloc((size_t)NN*64*2);
  int*   deg   = (int*)  alloc((size_t)NN*4);
  int*   cursor= (int*)  alloc((size_t)NN*4);
  int*   rowptr= (int*)  alloc((size_t)NN*4);
  int*   eids  = (int*)  alloc((size_t)E1N*4);
  int*   dsts  = (int*)  alloc((size_t)E1N*4);
  int*   parts = (int*)  alloc((size_t)256*4);
  float* x123  = (float*)alloc((size_t)NBATCH*192*4);
  float* t1    = (float*)alloc((size_t)NBATCH*64*4);
  float* t2    = (float*)alloc((size_t)NBATCH*32*4);
  (void)ws_size; (void)n_in; (void)in_sizes; (void)out_size;

  auto scan = [&](const int* dg, int n, int* ptr, int* cur){
    k_scan1<<<n/256,256,0,stream>>>(dg, ptr, parts);
    k_scan2<<<1,256,0,stream>>>(parts, n/256);
    k_scan3<<<n/256,256,0,stream>>>(parts, ptr, cur);
  };

  // ---- edge CSR by src (once; reused by all 3 convs) ----
  hipMemsetAsync(deg, 0, (size_t)NN*4, stream);
  k_count<<<cdiv(E1N,256),256,0,stream>>>(ei, deg, E1N);
  scan(deg, NN, rowptr, cursor);
  k_fill_edge<<<cdiv(E1N,256),256,0,stream>>>(ei, cursor, eids, dsts);
  k_cvt16<<<cdiv((long long)NN*16,256),256,0,stream>>>(x0, x016, NN*16);

  // ---- NNConv x3 ----
  auto run_nnconv = [&](const float* xin, const f16* xin16, int mi, int mo,
                        const float* const* P, float* outb, f16* out16){
    const float* W1=P[0]; const float* b1=P[1]; const float* W2=P[2];
    const float* b2=P[3]; const float* root=P[4]; const float* bias=P[5];
    k_edge_mlp<<<cdiv((long long)E1N*KH,256),256,0,stream>>>(ea, eids, W1, b1, hrelu);
    k_prep<<<cdiv((long long)NN*mo,256),256,0,stream>>>(xin, root, bias, b2, outb, bterm, mi, mo);
    const int S = (mi > 32) ? 2 : 1;
    for (int ob = 0; ob < mo; ob += OC){
      k_w2pack<<<cdiv((long long)128*S*512,256),256,0,stream>>>(W2, W2p, mi, mo, ob, S);
      dim3 g(NN/64, NCOLS/128);
      if (mi==16)      k_mgemm_mfma<16,1><<<g,256,0,stream>>>(xin16, W2p, Mc);
      else if (mi==32) k_mgemm_mfma<32,1><<<g,256,0,stream>>>(xin16, W2p, Mc);
      else             k_mgemm_mfma<64,2><<<g,256,0,stream>>>(xin16, W2p, Mc);
      k_msg_node<<<NN/4,256,0,stream>>>(rowptr, cursor, dsts, hrelu, Mc, bterm, outb, mo, ob);
    }
    if (out16) k_elu_both<<<cdiv((long long)NN*mo,256),256,0,stream>>>(outb, out16, NN*mo);
    else       k_elu<<<cdiv((long long)NN*mo,256),256,0,stream>>>(outb, NN*mo);
  };
  run_nnconv(x0, x016, 16, 32, nnp[0], hA, hA16);
  run_nnconv(hA, hA16, 32, 64, nnp[1], hB, hB16);
  run_nnconv(hB, hB16, 64, 64, nnp[2], hC, nullptr);

  // level-1 batch sum (sorted segments, no atomics)
  k_batchsum_seg<<<NBATCH,256,0,stream>>>(batch, hC, x123, NN, 0);

  // ---- levels 2 and 3 ----
  auto run_level = [&](const int* an, const int* ac, int A, const float* iso,
                       const int* eiL, int EL, const int* batchL,
                       const float* const* cA, const float* const* cB, int off123){
    // cluster CSR for pooling
    hipMemsetAsync(ldeg, 0, (size_t)NC2*4, stream);
    k_count<<<cdiv(A,256),256,0,stream>>>(ac, ldeg, A);
    scan(ldeg, NC2, aptr, acur);
    k_fill_assign<<<cdiv(A,256),256,0,stream>>>(an, ac, acur, ans, A);
    // dst CSR for GraphConv aggregation
    hipMemsetAsync(ldeg, 0, (size_t)NC2*4, stream);
    k_count<<<cdiv(EL,256),256,0,stream>>>(eiL + EL, ldeg, EL);
    scan(ldeg, NC2, dptr, dcur);
    k_fill_dst<<<cdiv(EL,256),256,0,stream>>>(eiL, dcur, dsrc, EL);
    // pooled features (mean + iso concat) -> h16
    k_pool_gather<<<NC2/4,256,0,stream>>>(aptr, acur, ans, hC, iso, h16);
    // gc layer 1 (din=128)
    k_packB_gc<<<cdiv((long long)8*4*512,256),256,0,stream>>>(cA[0], cA[1], BpGc, 4);
    k_gc_mfma<4><<<NC2/64,256,0,stream>>>(h16, BpGc, cA[2], ybuf, rbuf);
    k_gc_gather<true><<<NC2/4,256,0,stream>>>(dptr, dcur, dsrc, ybuf, rbuf, g16, nullptr);
    // gc layer 2 (din=64)
    k_packB_gc<<<cdiv((long long)8*2*512,256),256,0,stream>>>(cB[0], cB[1], BpGc, 2);
    k_gc_mfma<2><<<NC2/64,256,0,stream>>>(g16, BpGc, cB[2], ybuf, rbuf);
    k_gc_gather<false><<<NC2/4,256,0,stream>>>(dptr, dcur, dsrc, ybuf, rbuf, nullptr, gB);
    // batch sum
    k_batchsum_seg<<<NBATCH,256,0,stream>>>(batchL, gB, x123, NC2, off123);
  };
  run_level(a2n, a2c, 131072, iso2, ei2, 262144, b2arr, c4W, c5W, 64);
  run_level(a3n, a3c, 196608, iso3, ei3, 262144, b3arr, c6W, c7W, 128);

  // ---- FC head ----
  k_fc1<<<cdiv((long long)NBATCH*64,256),256,0,stream>>>(x123, fc1W, fc1b, t1);
  k_fc2<<<cdiv((long long)NBATCH*32,256),256,0,stream>>>(t1, fc2W, fc2b, t2);
  k_fc3<<<cdiv(NBATCH,256),256,0,stream>>>(t2, fc3W, fc3b, outp);
}

// Round 6
// 899.397 us; speedup vs baseline: 2.7977x; 1.3800x over previous
//
#include <hip/hip_runtime.h>
#include <math.h>

#define NN 16384      // nodes
#define E1N 65536     // edges level 1
#define NBATCH 256
#define NC2 65536     // clusters (level 2 and level 3)
#define KH 128        // edge-MLP hidden
#define OCSTR 136     // oc stride in fused LDS tile (f16; 272B = 17 x 16B)
#define NSTR 1096     // node stride (f16; 8*136+8 -> 16B-aligned, 4-dword bank shift)

typedef _Float16 f16;
typedef _Float16 f16x2 __attribute__((ext_vector_type(2)));
typedef _Float16 f16x8 __attribute__((ext_vector_type(8)));
typedef float    f32x4 __attribute__((ext_vector_type(4)));

__device__ __forceinline__ float elu1(float x){ return x > 0.f ? x : expm1f(x); }

__device__ __forceinline__ float dot2acc(f16x2 a, f16x2 b, float c){
#if __has_builtin(__builtin_amdgcn_fdot2)
  return __builtin_amdgcn_fdot2(a, b, c, false);
#else
  return fmaf((float)a[0], (float)b[0], fmaf((float)a[1], (float)b[1], c));
#endif
}

// ---------------- generic counting + 3-phase scan ----------------
__global__ __launch_bounds__(256) void k_count(const int* __restrict__ arr, int* __restrict__ cnt, int n){
  int i = blockIdx.x*256 + threadIdx.x;
  if (i < n) atomicAdd(&cnt[arr[i]], 1);
}

__global__ __launch_bounds__(256) void k_scan1(const int* __restrict__ deg,
    int* __restrict__ ptr, int* __restrict__ partials){
  __shared__ int buf[256];
  int i = blockIdx.x*256 + threadIdx.x, t = threadIdx.x;
  int v = deg[i];
  buf[t] = v; __syncthreads();
  for (int o = 1; o < 256; o <<= 1){
    int x = (t >= o) ? buf[t-o] : 0;
    __syncthreads(); buf[t] += x; __syncthreads();
  }
  ptr[i] = buf[t] - v;
  if (t == 255) partials[blockIdx.x] = buf[255];
}

__global__ __launch_bounds__(256) void k_scan2(int* __restrict__ partials, int nb){
  __shared__ int buf[256];
  int t = threadIdx.x;
  int v = (t < nb) ? partials[t] : 0;
  buf[t] = v; __syncthreads();
  for (int o = 1; o < 256; o <<= 1){
    int x = (t >= o) ? buf[t-o] : 0;
    __syncthreads(); buf[t] += x; __syncthreads();
  }
  if (t < nb) partials[t] = buf[t] - v;
}

__global__ __launch_bounds__(256) void k_scan3(const int* __restrict__ partials,
    int* __restrict__ ptr, int* __restrict__ cur){
  int i = blockIdx.x*256 + threadIdx.x;
  int v = ptr[i] + partials[blockIdx.x];
  ptr[i] = v; cur[i] = v;
}

// ---------------- CSR fills ----------------
__global__ __launch_bounds__(256) void k_fill_edge(const int* __restrict__ ei, int* __restrict__ cursor,
    int* __restrict__ eids, int* __restrict__ srcs, int* __restrict__ dsts){
  int e = blockIdx.x*256 + threadIdx.x;
  if (e >= E1N) return;
  int s = ei[e];
  int p = atomicAdd(&cursor[s], 1);
  eids[p] = e; srcs[p] = s; dsts[p] = ei[E1N + e];
}

__global__ __launch_bounds__(256) void k_fill_dst(const int* __restrict__ eiL, int* __restrict__ cur,
    int* __restrict__ dsrc, int EL){
  int e = blockIdx.x*256 + threadIdx.x;
  if (e >= EL) return;
  int d = eiL[EL + e];
  int p = atomicAdd(&cur[d], 1);
  dsrc[p] = eiL[e];
}

__global__ __launch_bounds__(256) void k_fill_assign(const int* __restrict__ an, const int* __restrict__ ac,
    int* __restrict__ cur, int* __restrict__ an_sorted, int A){
  int a = blockIdx.x*256 + threadIdx.x;
  if (a >= A) return;
  int c = ac[a];
  int p = atomicAdd(&cur[c], 1);
  an_sorted[p] = an[a];
}

// ---------------- small converts ----------------
__global__ __launch_bounds__(256) void k_cvt16(const float* __restrict__ v, f16* __restrict__ o, int n){
  int t = blockIdx.x*256 + threadIdx.x;
  if (t < n) o[t] = (f16)v[t];
}

__global__ __launch_bounds__(256) void k_elu_both(float* __restrict__ v, f16* __restrict__ v16, int n){
  int t = blockIdx.x*256 + threadIdx.x;
  if (t < n){ float r = elu1(v[t]); v[t] = r; v16[t] = (f16)r; }
}

__global__ __launch_bounds__(256) void k_elu(float* __restrict__ v, int n){
  int t = blockIdx.x*256 + threadIdx.x;
  if (t < n) v[t] = elu1(v[t]);
}

// ---------------- NNConv pieces ----------------
// hrelu[p,k] (CSR-sorted edge order) = relu(b1[k] + sum_i ea[eids[p],i]*W1[i,k])
__global__ __launch_bounds__(256) void k_edge_mlp(const float* __restrict__ ea,
    const int* __restrict__ eids,
    const float* __restrict__ W1, const float* __restrict__ b1,
    f16* __restrict__ hrelu){
  int t = blockIdx.x*256 + threadIdx.x;
  if (t >= E1N*KH) return;
  int p = t >> 7, k = t & 127;
  const float* row = ea + (size_t)eids[p]*7;
  float acc = b1[k];
  #pragma unroll
  for (int i=0;i<7;i++) acc = fmaf(row[i], W1[i*KH+k], acc);
  hrelu[t] = (f16)fmaxf(acc, 0.f);
}

// pack [root | b2] (each MI x MO fp32) into B-frag order, N = 2*MO cols
__global__ __launch_bounds__(256) void k_packPrep(const float* __restrict__ root,
    const float* __restrict__ b2, f16* __restrict__ Bp, int mi, int mo, int S, int NB){
  int t = blockIdx.x*256 + threadIdx.x;
  if (t >= NB*S*512) return;
  int j = t & 7, l = (t >> 3) & 63, cs = t >> 9;
  int s = cs % S, c = cs / S;
  int k_in = s*32 + ((l>>4)<<3) + j;
  int n = c*16 + (l & 15);
  float v = 0.f;
  if (k_in < mi) v = (n < mo) ? root[k_in*mo + n] : b2[k_in*mo + (n - mo)];
  Bp[t] = (f16)v;
}

// outb[n,o] = bias[o] + (x@root)[n,o]; bterm[n,o] = (x@b2)[n,o]   via MFMA
template<int MI, int S, int NB, int MO>
__global__ __launch_bounds__(256) void k_prep_mfma(const f16* __restrict__ A,
    const f16* __restrict__ Bp, const float* __restrict__ bias,
    float* __restrict__ outb, float* __restrict__ bterm){
  int l = threadIdx.x & 63, w = threadIdx.x >> 6;
  int r0 = blockIdx.x*64 + w*16;
  const f16* arow = A + (size_t)(r0 + (l & 15))*MI;
  f16x8 a[S];
  #pragma unroll
  for (int s=0;s<S;s++){
    int koff = s*32 + ((l>>4)<<3);
    if (koff < MI) a[s] = *(const f16x8*)(arow + koff);
    else           a[s] = (f16x8){0,0,0,0,0,0,0,0};
  }
  #pragma unroll
  for (int c=0;c<NB;c++){
    f32x4 acc = (f32x4){0.f,0.f,0.f,0.f};
    #pragma unroll
    for (int s=0;s<S;s++){
      f16x8 b = *(const f16x8*)(Bp + ((size_t)(c*S + s)*64 + l)*8);
      acc = __builtin_amdgcn_mfma_f32_16x16x32_f16(a[s], b, acc, 0, 0, 0);
    }
    int col = c*16 + (l & 15);
    #pragma unroll
    for (int r=0;r<4;r++){
      int row = r0 + ((l>>4)<<2) + r;
      if (col < MO) outb[(size_t)row*MO + col] = acc[r] + bias[col];
      else          bterm[(size_t)row*MO + (col - MO)] = acc[r];
    }
  }
}

// pack FULL W2 into B-frag order; logical cols = mo*128, col -> (oc=col>>7, k=col&127)
__global__ __launch_bounds__(256) void k_w2pack_full(const float* __restrict__ W2,
    f16* __restrict__ Bp, int mi, int mo, int S){
  int t = blockIdx.x*256 + threadIdx.x;
  if (t >= mo*8*S*512) return;
  int j = t & 7, l = (t >> 3) & 63, cs = t >> 9;
  int s = cs % S, q = cs / S;
  int oc = q >> 3;
  int k  = (q & 7)*16 + (l & 15);
  int i  = s*32 + ((l>>4)<<3) + j;
  float v = (i < mi) ? W2[(size_t)k*mi*mo + (size_t)i*mo + oc] : 0.f;
  Bp[t] = (f16)v;
}

// FUSED NNConv: block = 16 CSR-consecutive nodes. Loop oc-chunks of 8:
//   stage 1: M[16n][8oc][128k] = A @ W2p chunk via MFMA -> LDS
//   stage 2: per edge in block's CSR span: msg = bterm + <hrelu, M[src]>; atomic to dst
template<int MI, int S, int MO>
__global__ __launch_bounds__(256) void k_nnconv_fused(const f16* __restrict__ xin16,
    const f16* __restrict__ W2p,
    const int* __restrict__ rowptr, const int* __restrict__ rowend,
    const int* __restrict__ srcs, const int* __restrict__ dsts,
    const f16* __restrict__ hrelu, const float* __restrict__ bterm,
    float* __restrict__ outb){
  __shared__ __align__(16) f16 M[16*NSTR];   // 35,072 B
  int l = threadIdx.x & 63, w = threadIdx.x >> 6;
  int n0 = blockIdx.x * 16;
  int estart = rowptr[n0];
  int eend   = rowend[n0 + 15];
  if (estart >= eend) return;              // block-uniform
  // A fragments for the 16 nodes (reused across all chunks)
  const f16* arow = xin16 + (size_t)(n0 + (l & 15))*MI;
  f16x8 a[S];
  #pragma unroll
  for (int s=0;s<S;s++){
    int koff = s*32 + ((l>>4)<<3);
    if (koff < MI) a[s] = *(const f16x8*)(arow + koff);
    else           a[s] = (f16x8){0,0,0,0,0,0,0,0};
  }
  int eslot = l >> 3, oc = l & 7;
  int passes = (eend - estart + 31) >> 5;  // 32 edges per block-pass
  const int NCHUNK = MO/8;
  for (int c = 0; c < NCHUNK; c++){
    // ---- stage 1: MFMA into LDS ----
    #pragma unroll
    for (int t=0;t<16;t++){
      int q = c*64 + w*16 + t;
      f32x4 acc = (f32x4){0.f,0.f,0.f,0.f};
      #pragma unroll
      for (int s=0;s<S;s++){
        f16x8 b = *(const f16x8*)(W2p + ((size_t)(q*S + s)*64 + l)*8);
        acc = __builtin_amdgcn_mfma_f32_16x16x32_f16(a[s], b, acc, 0, 0, 0);
      }
      int ocl = w*2 + (t>>3);              // local oc 0..7
      int k0  = (t&7)*16 + (l & 15);       // k 0..127
      f16* mp = &M[ocl*OCSTR + k0];
      #pragma unroll
      for (int r=0;r<4;r++)
        mp[(size_t)(((l>>4)<<2) + r)*NSTR] = (f16)acc[r];
    }
    __syncthreads();
    // ---- stage 2: consume edges ----
    for (int p = 0; p < passes; p++){
      int e = estart + p*32 + w*8 + eslot;
      if (e < eend){
        int s_ = srcs[e];
        int ln = s_ - n0;
        float acc = bterm[(size_t)s_*MO + c*8 + oc];
        const f16x8* hr = (const f16x8*)(hrelu + (size_t)e*KH);
        const f16* mrow = &M[(size_t)ln*NSTR + oc*OCSTR];
        #pragma unroll 4
        for (int kk=0; kk<16; kk++){
          f16x8 h8 = hr[kk];
          f16x8 m8 = *(const f16x8*)(mrow + kk*8);
          #pragma unroll
          for (int j=0;j<4;j++){
            f16x2 hp = {h8[2*j], h8[2*j+1]};
            f16x2 mp2 = {m8[2*j], m8[2*j+1]};
            acc = dot2acc(hp, mp2, acc);
          }
        }
        atomicAdd(&outb[(size_t)dsts[e]*MO + c*8 + oc], acc);
      }
    }
    __syncthreads();
  }
}

// ---------------- pooling via cluster-CSR (no atomics) ----------------
__global__ __launch_bounds__(256) void k_pool_gather(const int* __restrict__ aptr,
    const int* __restrict__ aend, const int* __restrict__ an_sorted,
    const float* __restrict__ h, const float* __restrict__ iso,
    f16* __restrict__ h16){
  int l = threadIdx.x & 63, w = threadIdx.x >> 6;
  int c = blockIdx.x*4 + w;
  int st = aptr[c], en = aend[c];
  float acc = 0.f;
  int e = st;
  for (; e+1 < en; e += 2){
    int n0 = an_sorted[e], n1 = an_sorted[e+1];
    acc += h[(size_t)n0*64 + l];
    acc += h[(size_t)n1*64 + l];
  }
  if (e < en) acc += h[(size_t)an_sorted[e]*64 + l];
  int cnt = en - st;
  float val = (cnt > 0) ? acc / (float)cnt : 0.f;
  h16[(size_t)c*128 + l] = (f16)val;
  h16[(size_t)c*128 + 64 + l] = (f16)iso[(size_t)c*64 + l];
}

// ---------------- GraphConv ----------------
__global__ __launch_bounds__(256) void k_packB_gc(const float* __restrict__ Wrel,
    const float* __restrict__ Wroot, f16* __restrict__ Bp, int S){
  int t = blockIdx.x*256 + threadIdx.x;
  if (t >= 8*S*512) return;
  int j = t & 7, l = (t >> 3) & 63, cs = t >> 9;
  int s = cs % S, c = cs / S;
  int k = s*32 + ((l>>4)<<3) + j;
  int n = (c<<4) + (l & 15);
  float v = (n < 64) ? Wrel[k*64 + n] : Wroot[k*64 + (n - 64)];
  Bp[t] = (f16)v;
}

template<int S>
__global__ __launch_bounds__(256) void k_gc_mfma(const f16* __restrict__ A,
    const f16* __restrict__ Bp, const float* __restrict__ bias,
    float* __restrict__ y, float* __restrict__ rbuf){
  int l = threadIdx.x & 63, w = threadIdx.x >> 6;
  int r0 = blockIdx.x*64 + w*16;
  const f16* arow = A + (size_t)(r0 + (l & 15))*(S*32);
  f16x8 a[S];
  #pragma unroll
  for (int s=0;s<S;s++) a[s] = *(const f16x8*)(arow + s*32 + ((l>>4)<<3));
  f32x4 acc[8];
  #pragma unroll
  for (int c=0;c<8;c++) acc[c] = (f32x4){0.f,0.f,0.f,0.f};
  #pragma unroll
  for (int c=0;c<8;c++){
    #pragma unroll
    for (int s=0;s<S;s++){
      f16x8 b = *(const f16x8*)(Bp + ((size_t)(c*S + s)*64 + l)*8);
      acc[c] = __builtin_amdgcn_mfma_f32_16x16x32_f16(a[s], b, acc[c], 0, 0, 0);
    }
  }
  #pragma unroll
  for (int c=0;c<8;c++){
    int col = c*16 + (l & 15);
    #pragma unroll
    for (int r=0;r<4;r++){
      int row = r0 + ((l>>4)<<2) + r;
      if (col < 64) y[(size_t)row*64 + col] = acc[c][r];
      else          rbuf[(size_t)row*64 + (col-64)] = acc[c][r] + bias[col-64];
    }
  }
}

template<bool F16OUT>
__global__ __launch_bounds__(256) void k_gc_gather(const int* __restrict__ dptr,
    const int* __restrict__ dend, const int* __restrict__ dsrc,
    const float* __restrict__ y, const float* __restrict__ rbuf,
    f16* __restrict__ o16, float* __restrict__ o32){
  int l = threadIdx.x & 63, w = threadIdx.x >> 6;
  int n = blockIdx.x*4 + w;
  int st = dptr[n], en = dend[n];
  float acc = rbuf[(size_t)n*64 + l];
  int e = st;
  for (; e+1 < en; e += 2){
    int s0 = dsrc[e], s1 = dsrc[e+1];
    acc += y[(size_t)s0*64 + l];
    acc += y[(size_t)s1*64 + l];
  }
  if (e < en) acc += y[(size_t)dsrc[e]*64 + l];
  float r = elu1(acc);
  if (F16OUT) o16[(size_t)n*64 + l] = (f16)r;
  else        o32[(size_t)n*64 + l] = r;
}

// ---------------- sorted-segment batch sum ----------------
__device__ __forceinline__ int lowerb(const int* __restrict__ a, int n, int key){
  int lo = 0, hi = n;
  while (lo < hi){ int m = (lo + hi) >> 1; if (a[m] < key) lo = m + 1; else hi = m; }
  return lo;
}

__global__ __launch_bounds__(256) void k_batchsum_seg(const int* __restrict__ batch,
    const float* __restrict__ h, float* __restrict__ x123, int n_nodes, int off){
  __shared__ float red[4][64];
  int b = blockIdx.x;
  int lo = lowerb(batch, n_nodes, b);
  int hi = lowerb(batch, n_nodes, b+1);
  int col = threadIdx.x & 63, wq = threadIdx.x >> 6;
  float acc = 0.f;
  for (int n = lo + wq; n < hi; n += 4) acc += h[(size_t)n*64 + col];
  red[wq][col] = acc;
  __syncthreads();
  if (threadIdx.x < 64){
    float s = red[0][threadIdx.x] + red[1][threadIdx.x] + red[2][threadIdx.x] + red[3][threadIdx.x];
    x123[b*192 + off + threadIdx.x] = s;
  }
}

// ---------------- FC head ----------------
__global__ __launch_bounds__(256) void k_fc1(const float* __restrict__ x123,
    const float* __restrict__ W, const float* __restrict__ b, float* __restrict__ t1){
  int t = blockIdx.x*256 + threadIdx.x;
  if (t >= NBATCH*64) return;
  int bb = t >> 6, o = t & 63;
  const float* xr = x123 + bb*192;
  float acc = b[o];
  for (int j=0;j<192;j++) acc = fmaf(xr[j], W[j*64+o] + W[(192+j)*64+o], acc);
  t1[t] = elu1(acc);
}

__global__ __launch_bounds__(256) void k_fc2(const float* __restrict__ t1,
    const float* __restrict__ W, const float* __restrict__ b, float* __restrict__ t2){
  int t = blockIdx.x*256 + threadIdx.x;
  if (t >= NBATCH*32) return;
  int bb = t >> 5, o = t & 31;
  float acc = b[o];
  for (int j=0;j<64;j++) acc = fmaf(t1[bb*64+j], W[j*32+o], acc);
  t2[t] = elu1(acc);
}

__global__ __launch_bounds__(256) void k_fc3(const float* __restrict__ t2,
    const float* __restrict__ W, const float* __restrict__ b, float* __restrict__ out){
  int t = blockIdx.x*256 + threadIdx.x;
  if (t >= NBATCH) return;
  float acc = b[0];
  for (int j=0;j<32;j++) acc = fmaf(t2[t*32+j], W[j], acc);
  out[t] = acc;
}

static inline int cdiv(long long a, int b){ return (int)((a + b - 1) / b); }

extern "C" void kernel_launch(void* const* d_in, const int* in_sizes, int n_in,
                              void* d_out, int out_size, void* d_ws, size_t ws_size,
                              hipStream_t stream) {
  const float* x0    = (const float*)d_in[0];
  const int*   ei    = (const int*)d_in[1];
  const float* ea    = (const float*)d_in[2];
  const int*   batch = (const int*)d_in[3];
  const int*   a2n   = (const int*)d_in[4];
  const int*   a2c   = (const int*)d_in[5];
  const float* iso2  = (const float*)d_in[6];
  const int*   ei2   = (const int*)d_in[7];
  const int*   b2arr = (const int*)d_in[8];
  const int*   a3n   = (const int*)d_in[9];
  const int*   a3c   = (const int*)d_in[10];
  const float* iso3  = (const float*)d_in[11];
  const int*   ei3   = (const int*)d_in[12];
  const int*   b3arr = (const int*)d_in[13];
  const float* nnp[3][6];
  for (int c=0;c<3;c++) for (int p=0;p<6;p++) nnp[c][p] = (const float*)d_in[14 + 6*c + p];
  const float* c4W[3]; const float* c5W[3]; const float* c6W[3]; const float* c7W[3];
  for (int p=0;p<3;p++){ c4W[p]=(const float*)d_in[32+p]; c5W[p]=(const float*)d_in[35+p];
                         c6W[p]=(const float*)d_in[38+p]; c7W[p]=(const float*)d_in[41+p]; }
  const float* fc1W=(const float*)d_in[44]; const float* fc1b=(const float*)d_in[45];
  const float* fc2W=(const float*)d_in[46]; const float* fc2b=(const float*)d_in[47];
  const float* fc3W=(const float*)d_in[48]; const float* fc3b=(const float*)d_in[49];
  float* outp = (float*)d_out;

  // ---- workspace carve ----
  char* ws = (char*)d_ws; size_t off = 0;
  auto alloc = [&](size_t bytes)->void*{ void* p = ws + off; off += (bytes + 255) & ~(size_t)255; return p; };
  const size_t SZ_R0 = (size_t)92*1024*1024;
  char* r0 = (char*)alloc(SZ_R0);
  // phase-1 view (NNConv): hrelu 16MB | W2p ~1MB | prepB 16KB | bterm 4MB
  f16*   hrelu = (f16*)r0;
  f16*   W2p   = (f16*)(r0 + (size_t)E1N*KH*2);
  f16*   prepB = (f16*)(r0 + (size_t)E1N*KH*2 + 2*1024*1024);
  float* bterm = (float*)(r0 + (size_t)E1N*KH*2 + 2*1024*1024 + 64*1024);
  // phase-2 view (levels)
  size_t o2 = 0;
  auto a2 = [&](size_t bytes)->char*{ char* p = r0 + o2; o2 += (bytes + 255) & ~(size_t)255; return p; };
  f16*   h16   = (f16*)  a2((size_t)NC2*128*2);   // 16 MB
  float* ybuf  = (float*)a2((size_t)NC2*64*4);    // 16 MB
  float* rbuf  = (float*)a2((size_t)NC2*64*4);    // 16 MB
  float* gB    = (float*)a2((size_t)NC2*64*4);    // 16 MB
  f16*   g16   = (f16*)  a2((size_t)NC2*64*2);    //  8 MB
  f16*   BpGc  = (f16*)  a2((size_t)8*4*512*2);   // 32 KB
  int*   aptr  = (int*)  a2((size_t)NC2*4);
  int*   acur  = (int*)  a2((size_t)NC2*4);
  int*   dptr  = (int*)  a2((size_t)NC2*4);
  int*   dcur  = (int*)  a2((size_t)NC2*4);
  int*   ldeg  = (int*)  a2((size_t)NC2*4);
  int*   ans   = (int*)  a2((size_t)196608*4);
  int*   dsrc  = (int*)  a2((size_t)262144*4);
  // persistent
  float* hA    = (float*)alloc((size_t)NN*32*4);
  float* hB    = (float*)alloc((size_t)NN*64*4);
  float* hC    = (float*)alloc((size_t)NN*64*4);
  f16*   x016  = (f16*)  alloc((size_t)NN*16*2);
  f16*   hA16  = (f16*)  alloc((size_t)NN*32*2);
  f16*   hB16  = (f16*)  alloc((size_t)NN*64*2);
  int*   deg   = (int*)  alloc((size_t)NN*4);
  int*   cursor= (int*)  alloc((size_t)NN*4);
  int*   rowptr= (int*)  alloc((size_t)NN*4);
  int*   eids  = (int*)  alloc((size_t)E1N*4);
  int*   srcs  = (int*)  alloc((size_t)E1N*4);
  int*   dsts  = (int*)  alloc((size_t)E1N*4);
  int*   parts = (int*)  alloc((size_t)256*4);
  float* x123  = (float*)alloc((size_t)NBATCH*192*4);
  float* t1    = (float*)alloc((size_t)NBATCH*64*4);
  float* t2    = (float*)alloc((size_t)NBATCH*32*4);
  (void)ws_size; (void)n_in; (void)in_sizes; (void)out_size;

  auto scan = [&](const int* dg, int n, int* ptr, int* cur){
    k_scan1<<<n/256,256,0,stream>>>(dg, ptr, parts);
    k_scan2<<<1,256,0,stream>>>(parts, n/256);
    k_scan3<<<n/256,256,0,stream>>>(parts, ptr, cur);
  };

  // ---- edge CSR by src (once; reused by all 3 convs) ----
  hipMemsetAsync(deg, 0, (size_t)NN*4, stream);
  k_count<<<cdiv(E1N,256),256,0,stream>>>(ei, deg, E1N);
  scan(deg, NN, rowptr, cursor);
  k_fill_edge<<<cdiv(E1N,256),256,0,stream>>>(ei, cursor, eids, srcs, dsts);
  k_cvt16<<<cdiv((long long)NN*16,256),256,0,stream>>>(x0, x016, NN*16);

  // ---- NNConv x3 (fused) ----
  auto run_nnconv = [&](const f16* xin16, int mi, int mo,
                        const float* const* P, float* outb, f16* out16){
    const float* W1=P[0]; const float* b1=P[1]; const float* W2=P[2];
    const float* b2=P[3]; const float* root=P[4]; const float* bias=P[5];
    const int S = (mi > 32) ? 2 : 1;
    const int NB = (2*mo)/16;
    k_edge_mlp<<<cdiv((long long)E1N*KH,256),256,0,stream>>>(ea, eids, W1, b1, hrelu);
    k_packPrep<<<cdiv((long long)NB*S*512,256),256,0,stream>>>(root, b2, prepB, mi, mo, S, NB);
    if (mi==16)      k_prep_mfma<16,1,4,32><<<NN/64,256,0,stream>>>(xin16, prepB, bias, outb, bterm);
    else if (mi==32) k_prep_mfma<32,1,8,64><<<NN/64,256,0,stream>>>(xin16, prepB, bias, outb, bterm);
    else             k_prep_mfma<64,2,8,64><<<NN/64,256,0,stream>>>(xin16, prepB, bias, outb, bterm);
    k_w2pack_full<<<cdiv((long long)mo*8*S*512,256),256,0,stream>>>(W2, W2p, mi, mo, S);
    if (mi==16)      k_nnconv_fused<16,1,32><<<NN/16,256,0,stream>>>(xin16, W2p, rowptr, cursor, srcs, dsts, hrelu, bterm, outb);
    else if (mi==32) k_nnconv_fused<32,1,64><<<NN/16,256,0,stream>>>(xin16, W2p, rowptr, cursor, srcs, dsts, hrelu, bterm, outb);
    else             k_nnconv_fused<64,2,64><<<NN/16,256,0,stream>>>(xin16, W2p, rowptr, cursor, srcs, dsts, hrelu, bterm, outb);
    if (out16) k_elu_both<<<cdiv((long long)NN*mo,256),256,0,stream>>>(outb, out16, NN*mo);
    else       k_elu<<<cdiv((long long)NN*mo,256),256,0,stream>>>(outb, NN*mo);
  };
  run_nnconv(x016, 16, 32, nnp[0], hA, hA16);
  run_nnconv(hA16, 32, 64, nnp[1], hB, hB16);
  run_nnconv(hB16, 64, 64, nnp[2], hC, nullptr);

  // level-1 batch sum
  k_batchsum_seg<<<NBATCH,256,0,stream>>>(batch, hC, x123, NN, 0);

  // ---- levels 2 and 3 ----
  auto run_level = [&](const int* an, const int* ac, int A, const float* iso,
                       const int* eiL, int EL, const int* batchL,
                       const float* const* cA, const float* const* cB, int off123){
    hipMemsetAsync(ldeg, 0, (size_t)NC2*4, stream);
    k_count<<<cdiv(A,256),256,0,stream>>>(ac, ldeg, A);
    scan(ldeg, NC2, aptr, acur);
    k_fill_assign<<<cdiv(A,256),256,0,stream>>>(an, ac, acur, ans, A);
    hipMemsetAsync(ldeg, 0, (size_t)NC2*4, stream);
    k_count<<<cdiv(EL,256),256,0,stream>>>(eiL + EL, ldeg, EL);
    scan(ldeg, NC2, dptr, dcur);
    k_fill_dst<<<cdiv(EL,256),256,0,stream>>>(eiL, dcur, dsrc, EL);
    k_pool_gather<<<NC2/4,256,0,stream>>>(aptr, acur, ans, hC, iso, h16);
    k_packB_gc<<<cdiv((long long)8*4*512,256),256,0,stream>>>(cA[0], cA[1], BpGc, 4);
    k_gc_mfma<4><<<NC2/64,256,0,stream>>>(h16, BpGc, cA[2], ybuf, rbuf);
    k_gc_gather<true><<<NC2/4,256,0,stream>>>(dptr, dcur, dsrc, ybuf, rbuf, g16, nullptr);
    k_packB_gc<<<cdiv((long long)8*2*512,256),256,0,stream>>>(cB[0], cB[1], BpGc, 2);
    k_gc_mfma<2><<<NC2/64,256,0,stream>>>(g16, BpGc, cB[2], ybuf, rbuf);
    k_gc_gather<false><<<NC2/4,256,0,stream>>>(dptr, dcur, dsrc, ybuf, rbuf, nullptr, gB);
    k_batchsum_seg<<<NBATCH,256,0,stream>>>(batchL, gB, x123, NC2, off123);
  };
  run_level(a2n, a2c, 131072, iso2, ei2, 262144, b2arr, c4W, c5W, 64);
  run_level(a3n, a3c, 196608, iso3, ei3, 262144, b3arr, c6W, c7W, 128);

  // ---- FC head ----
  k_fc1<<<cdiv((long long)NBATCH*64,256),256,0,stream>>>(x123, fc1W, fc1b, t1);
  k_fc2<<<cdiv((long long)NBATCH*32,256),256,0,stream>>>(t1, fc2W, fc2b, t2);
  k_fc3<<<cdiv(NBATCH,256),256,0,stream>>>(t2, fc3W, fc3b, outp);
}